// Round 10
// baseline (13957.034 us; speedup 1.0000x reference)
//
#include <hip/hip_runtime.h>

typedef __bf16 bf16_t;
typedef __bf16 bf16x8 __attribute__((ext_vector_type(8)));
typedef __bf16 bf16x4 __attribute__((ext_vector_type(4)));
typedef float  f32x4  __attribute__((ext_vector_type(4)));

#define DEV __device__ __forceinline__

constexpr int Bn = 256;
constexpr int Ln = 120;
constexpr int Dn = 192;
constexpr int Zn = 512;
constexpr int Hn = 1024;          // H = 2*Z
constexpr int KE = Zn + Hn;       // 1536: encoder lstm K  (x | h)
constexpr int KD = Zn + Dn + Hn;  // 1728: decoder lstm K  (xz | pose | h)
constexpr int NBLK = 256;         // persistent grid size
constexpr long HSLOT = (long)Bn * Hn;   // one h ring slot (elements)
constexpr long PSLOT = (long)Bn * Dn;   // one pose ring slot

DEV f32x4 mfma16(bf16x8 a, bf16x8 b, f32x4 c) {
  return __builtin_amdgcn_mfma_f32_16x16x32_bf16(a, b, c, 0, 0, 0);
}
DEV bf16x8 ldb8(const bf16_t* p) { return *reinterpret_cast<const bf16x8*>(p); }
DEV float sigf(float x) { return 1.f / (1.f + expf(-x)); }
DEV unsigned short b2u(bf16_t v) { union { bf16_t b; unsigned short u; } x; x.b = v; return x.u; }

// ---- ring-slot stores: write-through to MALL (coherence point). Readers use
// PLAIN CACHED loads on virgin addresses (ring slot never rewritten) -> first
// touch per XCD fetches fresh from MALL, rest hit L2. No fences, no inv.
DEV void st16c(bf16_t* p, bf16x8 v) {
  asm volatile("global_store_dwordx4 %0, %1, off sc0 sc1" :: "v"(p), "v"(v) : "memory");
}
DEV void st8c(bf16_t* p, bf16x4 v) {
  asm volatile("global_store_dwordx2 %0, %1, off sc0 sc1" :: "v"(p), "v"(v) : "memory");
}
DEV void st2c(bf16_t* p, unsigned short v) {
  asm volatile("global_store_short %0, %1, off sc0 sc1" :: "v"(p), "v"(v) : "memory");
}

// ---- grid barrier: pure relaxed, distributed arrive (R4-proven ~4us).
// No acquire fence: freshness comes from virgin ring addresses, not from inv.
DEV void gbar(unsigned* bar, unsigned epoch, int bid) {
  asm volatile("s_waitcnt vmcnt(0)" ::: "memory");  // drain this wave's sc1 stores
  __syncthreads();                                  // all waves drained + arrived
  if (threadIdx.x == 0) {
    int g = bid & 7;                                // 32 blocks per group
    unsigned a = __hip_atomic_fetch_add(bar + g * 16, 1u, __ATOMIC_RELAXED,
                                        __HIP_MEMORY_SCOPE_AGENT);
    if (a == epoch * 32u - 1u) {
      unsigned b = __hip_atomic_fetch_add(bar + 128, 1u, __ATOMIC_RELAXED,
                                          __HIP_MEMORY_SCOPE_AGENT);
      if (b == epoch * 8u - 1u)
        __hip_atomic_store(bar + 192, epoch, __ATOMIC_RELAXED, __HIP_MEMORY_SCOPE_AGENT);
    }
    while (__hip_atomic_load(bar + 192, __ATOMIC_RELAXED, __HIP_MEMORY_SCOPE_AGENT) < epoch)
      __builtin_amdgcn_s_sleep(2);
  }
  __syncthreads();
}

// ---------------- merged weight-cast kernel (f32 -> bf16, 10 tensors) ----------------
__global__ void k_cast_all(
    const float* __restrict__ s0, const float* __restrict__ s1,
    const float* __restrict__ s2, const float* __restrict__ s3,
    const float* __restrict__ s4, const float* __restrict__ s5,
    const float* __restrict__ s6, const float* __restrict__ s7,
    const float* __restrict__ s8, const float* __restrict__ s9,
    bf16_t* __restrict__ d0, bf16_t* __restrict__ d1,
    bf16_t* __restrict__ d2, bf16_t* __restrict__ d3,
    bf16_t* __restrict__ d4, bf16_t* __restrict__ d5,
    bf16_t* __restrict__ d6, bf16_t* __restrict__ d7,
    bf16_t* __restrict__ d8, bf16_t* __restrict__ d9) {
  const long TOT = 1646592;  // total float4 groups
  for (long gidx = blockIdx.x * blockDim.x + threadIdx.x; gidx < TOT;
       gidx += (long)gridDim.x * blockDim.x) {
    const float* s; bf16_t* d; long r = gidx;
    if      (r < 24576)                      { s = s0; d = d0; }
    else if ((r -= 24576)   < 524288)        { s = s1; d = d1; }
    else if ((r -= 524288)  < 524288)        { s = s2; d = d2; }
    else if ((r -= 524288)  < 131072)        { s = s3; d = d3; }
    else if ((r -= 131072)  < 131072)        { s = s4; d = d4; }
    else if ((r -= 131072)  < 65536)         { s = s5; d = d5; }
    else if ((r -= 65536)   < 65536)         { s = s6; d = d6; }
    else if ((r -= 65536)   < 24576)         { s = s7; d = d7; }
    else if ((r -= 24576)   < 131072)        { s = s8; d = d8; }
    else    { r -= 131072;                     s = s9; d = d9; }
    float4 v = reinterpret_cast<const float4*>(s)[r];
    bf16x4 o;
    o[0] = (bf16_t)v.x; o[1] = (bf16_t)v.y; o[2] = (bf16_t)v.z; o[3] = (bf16_t)v.w;
    *reinterpret_cast<bf16x4*>(d + 4 * r) = o;
  }
}

// ---------------- layernorm over (L,D) per sample + x passthrough ----------------
__global__ void k_layernorm(const float* __restrict__ x, const float* __restrict__ w,
                            const float* __restrict__ bsh, float* __restrict__ out0,
                            bf16_t* __restrict__ xn) {
  const int n = Ln * Dn;  // 23040
  int b = blockIdx.x;
  const float* xb = x + (long)b * n;
  float s = 0.f, s2 = 0.f;
  for (int i = threadIdx.x; i < n; i += 256) { float v = xb[i]; s += v; s2 += v * v; }
  for (int off = 32; off; off >>= 1) { s += __shfl_down(s, off); s2 += __shfl_down(s2, off); }
  __shared__ float sh[8];
  int wave = threadIdx.x >> 6, lane = threadIdx.x & 63;
  if (lane == 0) { sh[wave] = s; sh[4 + wave] = s2; }
  __syncthreads();
  if (threadIdx.x == 0) {
    float S = sh[0] + sh[1] + sh[2] + sh[3];
    float S2 = sh[4] + sh[5] + sh[6] + sh[7];
    float m = S / n;
    float var = fmaxf(S2 / n - m * m, 0.f);
    sh[0] = m; sh[1] = rsqrtf(var + 1e-5f);
  }
  __syncthreads();
  float m = sh[0], inv = sh[1];
  for (int i = threadIdx.x; i < n; i += 256) {
    float v = xb[i];
    out0[(long)b * n + i] = v;
    xn[(long)b * n + i] = (bf16_t)((v - m) * inv * w[i] + bsh[i]);
  }
}

// ---------------- generic bf16 MFMA GEMM: out = act(A @ W^T + bias) ----------------
template <int ACT, bool XSPERM>
__global__ __launch_bounds__(256) void k_gemm(
    const bf16_t* __restrict__ A, int lda,
    const bf16_t* __restrict__ W, int ldw,
    const float* __restrict__ bias,
    float* __restrict__ outF, long ldoF,
    bf16_t* __restrict__ outB, int ldoB,
    int K) {
  int lane = threadIdx.x & 63, wave = threadIdx.x >> 6;
  int l15 = lane & 15, q = lane >> 4;
  int m0 = blockIdx.x * 64 + (wave >> 1) * 32;
  int n0 = blockIdx.y * 64 + (wave & 1) * 32;
  f32x4 acc00 = {}, acc01 = {}, acc10 = {}, acc11 = {};
  const bf16_t* Ap = A + (long)(m0 + l15) * lda + q * 8;
  const bf16_t* Wp = W + (long)(n0 + l15) * ldw + q * 8;
  long a16 = (long)16 * lda, w16 = (long)16 * ldw;
  for (int k0 = 0; k0 < K; k0 += 32) {
    bf16x8 a0 = ldb8(Ap + k0);
    bf16x8 a1 = ldb8(Ap + a16 + k0);
    bf16x8 b0 = ldb8(Wp + k0);
    bf16x8 b1 = ldb8(Wp + w16 + k0);
    acc00 = mfma16(a0, b0, acc00);
    acc01 = mfma16(a0, b1, acc01);
    acc10 = mfma16(a1, b0, acc10);
    acc11 = mfma16(a1, b1, acc11);
  }
#pragma unroll
  for (int mi = 0; mi < 2; ++mi)
#pragma unroll
    for (int ni = 0; ni < 2; ++ni) {
      f32x4 acc = (mi == 0) ? (ni == 0 ? acc00 : acc01) : (ni == 0 ? acc10 : acc11);
#pragma unroll
      for (int r = 0; r < 4; ++r) {
        int m = m0 + mi * 16 + q * 4 + r;
        int nn = n0 + ni * 16 + l15;
        float v = acc[r] + bias[nn];
        if (ACT == 1) v = fmaxf(v, 0.f);
        if (outF) outF[(long)m * ldoF + nn] = v;
        if (outB) {
          long row = XSPERM ? ((long)(m % Ln) * Bn + m / Ln) : m;
          outB[row * (long)ldoB + nn] = (bf16_t)v;
        }
      }
    }
}

// ================= persistent encoder BiLSTM (h ring) =================
constexpr int ENC_CH = KE / 32;                          // 48 k-chunks
constexpr int ENC_SMEM_W = 2 * ENC_CH * 64 * 16;         // 98304 B
constexpr int ENC_SMEM_G = 4 * 64 * 33 * 4;              // 33792 B gate buffers
constexpr int ENC_SMEM = ENC_SMEM_W + ENC_SMEM_G + 128;  // 132224 B

__global__ __launch_bounds__(256, 1) void k_enc_persist(
    const bf16_t* __restrict__ xs,   // [L][B][Z]
    const float* __restrict__ WihF, const float* __restrict__ WhhF,
    const float* __restrict__ bihF, const float* __restrict__ bhhF,
    const float* __restrict__ WihB, const float* __restrict__ WhhB,
    const float* __restrict__ bihB, const float* __restrict__ bhhB,
    const int* __restrict__ lens,
    bf16_t* __restrict__ hringF,     // [Ln+1][B][H] ring, slot 0 zeroed
    bf16_t* __restrict__ hringB,
    bf16_t* __restrict__ pooledb, float* __restrict__ out_len,
    unsigned* bar) {
  extern __shared__ char smem[];
  bf16x8* Wl = (bf16x8*)smem;
  float* Gbuf = (float*)(smem + ENC_SMEM_W);
  float* bias_l = (float*)(smem + ENC_SMEM_W + ENC_SMEM_G);

  int bid = blockIdx.x;
  int dir = bid >> 7;
  int j0 = (bid & 127) * 8;
  const float* Wih = dir ? WihB : WihF;
  const float* Whh = dir ? WhhB : WhhF;
  const float* bih = dir ? bihB : bihF;
  const float* bhh = dir ? bhhB : bhhF;
  bf16_t* hring = dir ? hringB : hringF;

  int tid = threadIdx.x;
  // ---- stage weight slice into LDS (fragment-major), f32 -> bf16 on the fly
  for (int f = tid; f < 2 * ENC_CH * 64; f += 256) {
    int ni = f / (ENC_CH * 64);
    int rem = f - ni * (ENC_CH * 64);
    int c = rem >> 6, sub = rem & 63;
    int sl = sub & 15, sq = sub >> 4;
    int r = ni * 16 + sl;                      // local W row 0..31
    int grow = (r >> 3) * Hn + j0 + (r & 7);   // global row: gate*H + col
    int k = c * 32 + sq * 8;
    const float* src = (k < Zn) ? (Wih + (long)grow * Zn + k)
                                : (Whh + (long)grow * Hn + (k - Zn));
    bf16x8 v;
#pragma unroll
    for (int e = 0; e < 8; ++e) v[e] = (bf16_t)src[e];
    Wl[f] = v;
  }
  if (tid < 32) {
    int grow = (tid >> 3) * Hn + j0 + (tid & 7);
    bias_l[tid] = bih[grow] + bhh[grow];
  }
  if (bid == 0) out_len[tid] = (float)lens[tid];
  __syncthreads();

  int wave = tid >> 6, lane = tid & 63;
  int l15 = lane & 15, q = lane >> 4;
  int mrow = wave * 64 + l15;      // + mi*16 -> A-frag rows
  int m = wave * 64 + lane;        // pointwise: this thread owns batch row m
  int mylen = lens[m];
  float c_reg[8] = {}, h_reg[8] = {}, pool_reg[8] = {};
  float* Gw = Gbuf + wave * (64 * 33);
  const bf16x8* Wl0 = Wl;
  const bf16x8* Wl1 = Wl + ENC_CH * 64;

  for (int t = 0; t < Ln; ++t) {
    int tt = dir ? (Ln - 1 - t) : t;
    const bf16_t* xt = xs + (long)tt * Bn * Zn;
    const bf16_t* hprev = hring + (long)t * HSLOT;        // virgin-cached read
    bf16_t* hcur = hring + (long)(t + 1) * HSLOT;         // write-through

    f32x4 acc[4][2] = {};
    const bf16_t* xrow = xt + (long)mrow * Zn + q * 8;
    const bf16_t* hrow = hprev + (long)mrow * Hn + q * 8;
    // x part: plain cached loads (immutable)
    for (int c = 0; c < Zn / 32; ++c) {
      bf16x8 b0 = Wl0[c * 64 + lane];
      bf16x8 b1 = Wl1[c * 64 + lane];
#pragma unroll
      for (int mi = 0; mi < 4; ++mi) {
        bf16x8 a = ldb8(xrow + (long)mi * 16 * Zn + c * 32);
        acc[mi][0] = mfma16(a, b0, acc[mi][0]);
        acc[mi][1] = mfma16(a, b1, acc[mi][1]);
      }
    }
    // h part: plain cached loads on a virgin ring slot -> per-XCD single MALL
    // fetch, then L2 hits. No coherence ops needed.
    for (int c = Zn / 32; c < ENC_CH; ++c) {
      bf16x8 b0 = Wl0[c * 64 + lane];
      bf16x8 b1 = Wl1[c * 64 + lane];
      int hk = c * 32 - Zn;
#pragma unroll
      for (int mi = 0; mi < 4; ++mi) {
        bf16x8 a = ldb8(hrow + (long)mi * 16 * Hn + hk);
        acc[mi][0] = mfma16(a, b0, acc[mi][0]);
        acc[mi][1] = mfma16(a, b1, acc[mi][1]);
      }
    }
    // dump gates to wave-private LDS (row = m-local, col = gate*8 + j-local)
#pragma unroll
    for (int mi = 0; mi < 4; ++mi)
#pragma unroll
      for (int ni = 0; ni < 2; ++ni)
#pragma unroll
        for (int r = 0; r < 4; ++r)
          Gw[(mi * 16 + q * 4 + r) * 33 + ni * 16 + l15] = acc[mi][ni][r];
    __syncthreads();
    bool act = tt < mylen;
    const float* Gr = Gw + lane * 33;
    bf16x8 hpack;
#pragma unroll
    for (int jj = 0; jj < 8; ++jj) {
      float Gi = Gr[jj] + bias_l[jj];
      float Gf = Gr[8 + jj] + bias_l[8 + jj];
      float Gg = Gr[16 + jj] + bias_l[16 + jj];
      float Go = Gr[24 + jj] + bias_l[24 + jj];
      float cn = sigf(Gf) * c_reg[jj] + sigf(Gi) * tanhf(Gg);
      float hn = sigf(Go) * tanhf(cn);
      if (act) { c_reg[jj] = cn; h_reg[jj] = hn; pool_reg[jj] += hn; }
      hpack[jj] = (bf16_t)h_reg[jj];
    }
    st16c(hcur + (long)m * Hn + j0, hpack);
    if (t != Ln - 1) gbar(bar, (unsigned)(t + 1), bid);
  }
  // pooled / len  (bf16 for the mu/lv heads; kernel boundary handles coherence)
  bf16x8 pp;
#pragma unroll
  for (int jj = 0; jj < 8; ++jj) pp[jj] = (bf16_t)(pool_reg[jj] / (float)mylen);
  *(bf16x8*)(pooledb + (long)m * (2 * Hn) + dir * Hn + j0) = pp;
}

// ============ persistent decoder: LSTM + fused l1l2, h/pose rings ============
constexpr int DEC_CH = KD / 32;                          // 54 k-chunks
constexpr int DEC_SMEM_W = 2 * DEC_CH * 64 * 16;         // 110592 B
constexpr int DEC_SMEM_G = 4 * 32 * 33 * 4;              // 16896 B (also reused as t1 tile)
constexpr int DEC_SMEM = DEC_SMEM_W + DEC_SMEM_G + 128;  // 127616 B

__global__ __launch_bounds__(256, 1) void k_dec_persist(
    const bf16_t* __restrict__ xz,   // [B][Zn] immutable
    bf16_t* __restrict__ posering,   // [Ln+1][B][Dn] ring, slot 0 = pose0
    const float* __restrict__ dWih, const float* __restrict__ dWhh,
    const float* __restrict__ dbih, const float* __restrict__ dbhh,
    bf16_t* __restrict__ hring,      // [Ln+1][B][H] ring, slot 0 zeroed
    const bf16_t* __restrict__ l1w, const float* __restrict__ l1bias,
    const bf16_t* __restrict__ l2w, const float* __restrict__ l2bias,
    float* __restrict__ out_dec,
    unsigned* bar) {
  extern __shared__ char smem[];
  bf16x8* Wl = (bf16x8*)smem;
  float* Gbuf = (float*)(smem + DEC_SMEM_W);
  float* bias_l = (float*)(smem + DEC_SMEM_W + DEC_SMEM_G);

  int bid = blockIdx.x;
  int mbase = (bid >> 7) * 128;
  int j0 = (bid & 127) * 8;
  int tid = threadIdx.x;

  for (int f = tid; f < 2 * DEC_CH * 64; f += 256) {
    int ni = f / (DEC_CH * 64);
    int rem = f - ni * (DEC_CH * 64);
    int c = rem >> 6, sub = rem & 63;
    int sl = sub & 15, sq = sub >> 4;
    int r = ni * 16 + sl;
    int grow = (r >> 3) * Hn + j0 + (r & 7);
    int k = c * 32 + sq * 8;
    // K layout: [0,Zn) = xz, [Zn,Zn+Dn) = pose, [Zn+Dn,KD) = h  (CATD = Zn+Dn)
    const float* src = (k < Zn + Dn) ? (dWih + (long)grow * (Zn + Dn) + k)
                                     : (dWhh + (long)grow * Hn + (k - (Zn + Dn)));
    bf16x8 v;
#pragma unroll
    for (int e = 0; e < 8; ++e) v[e] = (bf16_t)src[e];
    Wl[f] = v;
  }
  if (tid < 32) {
    int grow = (tid >> 3) * Hn + j0 + (tid & 7);
    bias_l[tid] = dbih[grow] + dbhh[grow];
  }
  __syncthreads();

  int wave = tid >> 6, lane = tid & 63;
  int l15 = lane & 15, q = lane >> 4;
  int mrow = mbase + wave * 32 + l15;          // + mi*16
  int mpt = mbase + wave * 32 + (lane >> 1);   // pointwise m
  int jh = (lane & 1) * 4;                     // pointwise j-half
  float c_reg[4] = {};
  float* Gw = Gbuf + wave * (32 * 33);
  const bf16x8* Wl0 = Wl;
  const bf16x8* Wl1 = Wl + DEC_CH * 64;

  for (int t = 0; t < Ln; ++t) {
    const bf16_t* hprev = hring + (long)t * HSLOT;
    bf16_t* hcur = hring + (long)(t + 1) * HSLOT;
    const bf16_t* poset = posering + (long)t * PSLOT;
    bf16_t* posen = posering + (long)(t + 1) * PSLOT;

    // ---- phase 1: LSTM gates + pointwise (all loads plain cached)
    f32x4 acc[2][2] = {};
    const bf16_t* xrow = xz + (long)mrow * Zn + q * 8;
    const bf16_t* prow = poset + (long)mrow * Dn + q * 8;
    const bf16_t* hrow = hprev + (long)mrow * Hn + q * 8;
    for (int c = 0; c < Zn / 32; ++c) {          // 16 chunks: xz (immutable)
      bf16x8 b0 = Wl0[c * 64 + lane];
      bf16x8 b1 = Wl1[c * 64 + lane];
#pragma unroll
      for (int mi = 0; mi < 2; ++mi) {
        bf16x8 a = ldb8(xrow + (long)mi * 16 * Zn + c * 32);
        acc[mi][0] = mfma16(a, b0, acc[mi][0]);
        acc[mi][1] = mfma16(a, b1, acc[mi][1]);
      }
    }
    for (int c = Zn / 32; c < (Zn + Dn) / 32; ++c) {  // 6 chunks: pose ring
      bf16x8 b0 = Wl0[c * 64 + lane];
      bf16x8 b1 = Wl1[c * 64 + lane];
      int pk = c * 32 - Zn;
#pragma unroll
      for (int mi = 0; mi < 2; ++mi) {
        bf16x8 a = ldb8(prow + (long)mi * 16 * Dn + pk);
        acc[mi][0] = mfma16(a, b0, acc[mi][0]);
        acc[mi][1] = mfma16(a, b1, acc[mi][1]);
      }
    }
    for (int c = (Zn + Dn) / 32; c < DEC_CH; ++c) {   // 32 chunks: h ring
      bf16x8 b0 = Wl0[c * 64 + lane];
      bf16x8 b1 = Wl1[c * 64 + lane];
      int hk = c * 32 - (Zn + Dn);
#pragma unroll
      for (int mi = 0; mi < 2; ++mi) {
        bf16x8 a = ldb8(hrow + (long)mi * 16 * Hn + hk);
        acc[mi][0] = mfma16(a, b0, acc[mi][0]);
        acc[mi][1] = mfma16(a, b1, acc[mi][1]);
      }
    }
#pragma unroll
    for (int mi = 0; mi < 2; ++mi)
#pragma unroll
      for (int ni = 0; ni < 2; ++ni)
#pragma unroll
        for (int r = 0; r < 4; ++r)
          Gw[(mi * 16 + q * 4 + r) * 33 + ni * 16 + l15] = acc[mi][ni][r];
    __syncthreads();
    {
      const float* Gr = Gw + (lane >> 1) * 33 + jh;
      bf16x4 hp;
#pragma unroll
      for (int p = 0; p < 4; ++p) {
        float Gi = Gr[p] + bias_l[jh + p];
        float Gf = Gr[8 + p] + bias_l[8 + jh + p];
        float Gg = Gr[16 + p] + bias_l[16 + jh + p];
        float Go = Gr[24 + p] + bias_l[24 + jh + p];
        float cn = sigf(Gf) * c_reg[p] + sigf(Gi) * tanhf(Gg);
        c_reg[p] = cn;
        hp[p] = (bf16_t)(sigf(Go) * tanhf(cn));
      }
      st8c(hcur + (long)mpt * Hn + j0 + jh, hp);
    }
    gbar(bar, (unsigned)(2 * t + 1), bid);

    // ---- phase 2 (fused l1+l2): blocks 0..15 each own 16 batch rows.
    // t1 tile stays in LDS; pose goes to the next ring slot.
    if (bid < 16) {
      int r0 = bid * 16;
      // l1: each wave computes 8 N-tiles (128 cols) over K=1024
      f32x4 accl[8] = {};
      const bf16_t* ha = hcur + (long)(r0 + l15) * Hn + q * 8;
      const bf16_t* wb1 = l1w + (long)(wave * 128 + l15) * Hn + q * 8;
      for (int c = 0; c < Hn / 32; ++c) {
        bf16x8 a = ldb8(ha + c * 32);
#pragma unroll
        for (int nti = 0; nti < 8; ++nti) {
          bf16x8 b = ldb8(wb1 + (long)nti * 16 * Hn + c * 32);
          accl[nti] = mfma16(a, b, accl[nti]);
        }
      }
      bf16_t* t1l = (bf16_t*)Gbuf;               // [16][520] bf16 tile
#pragma unroll
      for (int nti = 0; nti < 8; ++nti) {
        int n = wave * 128 + nti * 16 + l15;
        float bb = l1bias[n];
#pragma unroll
        for (int r = 0; r < 4; ++r)
          t1l[(q * 4 + r) * 520 + n] = (bf16_t)fmaxf(accl[nti][r] + bb, 0.f);
      }
      __syncthreads();                           // block-local: t1 tile ready
      // l2: each wave computes 3 N-tiles (48 cols of 192) over K=512
      f32x4 acc2[3] = {};
      const bf16_t* ta = t1l + l15 * 520 + q * 8;
      const bf16_t* wb2 = l2w + (long)(wave * 48 + l15) * Zn + q * 8;
      for (int c = 0; c < Zn / 32; ++c) {
        bf16x8 a = *reinterpret_cast<const bf16x8*>(ta + c * 32);
#pragma unroll
        for (int i = 0; i < 3; ++i) {
          bf16x8 b = ldb8(wb2 + (long)i * 16 * Zn + c * 32);
          acc2[i] = mfma16(a, b, acc2[i]);
        }
      }
#pragma unroll
      for (int i = 0; i < 3; ++i) {
        int n = wave * 48 + i * 16 + l15;
        float bb = l2bias[n];
#pragma unroll
        for (int r = 0; r < 4; ++r) {
          int mm = r0 + q * 4 + r;
          float v = acc2[i][r] + bb;
          out_dec[(long)mm * (Ln * Dn) + (long)t * Dn + n] = v;
          st2c(posen + (long)mm * Dn + n, b2u((bf16_t)v));
        }
      }
    }
    if (t != Ln - 1) gbar(bar, (unsigned)(2 * t + 2), bid);
  }
}

// ---------------- z = eps * exp(0.5 lv) + mu ----------------
DEV unsigned rotl32(unsigned v, int s) { return (v << s) | (v >> (32 - s)); }

#define TF_R4(r0, r1, r2, r3)                       \
  x0 += x1; x1 = rotl32(x1, r0); x1 ^= x0;          \
  x0 += x1; x1 = rotl32(x1, r1); x1 ^= x0;          \
  x0 += x1; x1 = rotl32(x1, r2); x1 ^= x0;          \
  x0 += x1; x1 = rotl32(x1, r3); x1 ^= x0;

DEV float erfinv_xla(float x) {
  float w = -log1pf(-x * x);
  float p;
  if (w < 5.f) {
    w -= 2.5f;
    p = 2.81022636e-08f;
    p = fmaf(p, w, 3.43273939e-07f);
    p = fmaf(p, w, -3.5233877e-06f);
    p = fmaf(p, w, -4.39150654e-06f);
    p = fmaf(p, w, 0.00021858087f);
    p = fmaf(p, w, -0.00125372503f);
    p = fmaf(p, w, -0.00417768164f);
    p = fmaf(p, w, 0.246640727f);
    p = fmaf(p, w, 1.50140941f);
  } else {
    w = sqrtf(w) - 3.f;
    p = -0.000200214257f;
    p = fmaf(p, w, 0.000100950558f);
    p = fmaf(p, w, 0.00134934322f);
    p = fmaf(p, w, -0.00367342844f);
    p = fmaf(p, w, 0.00573950773f);
    p = fmaf(p, w, -0.0076224613f);
    p = fmaf(p, w, 0.00943887047f);
    p = fmaf(p, w, 1.00167406f);
    p = fmaf(p, w, 2.83297682f);
  }
  return p * x;
}

__global__ void k_z(const float* __restrict__ mu, const float* __restrict__ lv,
                    float* __restrict__ zf, bf16_t* __restrict__ zb) {
  int i = blockIdx.x * blockDim.x + threadIdx.x;  // 0..131071
  const unsigned ks0 = 0u, ks1 = 42u, ks2 = 0x1BD11BDAu ^ ks0 ^ ks1;
  unsigned x0 = 0u + ks0;
  unsigned x1 = (unsigned)i + ks1;
  TF_R4(13, 15, 26, 6);  x0 += ks1; x1 += ks2 + 1u;
  TF_R4(17, 29, 16, 24); x0 += ks2; x1 += ks0 + 2u;
  TF_R4(13, 15, 26, 6);  x0 += ks0; x1 += ks1 + 3u;
  TF_R4(17, 29, 16, 24); x0 += ks1; x1 += ks2 + 4u;
  TF_R4(13, 15, 26, 6);  x0 += ks2; x1 += ks0 + 5u;
  unsigned bits = x0 ^ x1;
  float f = __uint_as_float((bits >> 9) | 0x3F800000u) - 1.0f;
  float u = f * 2.0f + (-0.99999994f);
  u = fmaxf(u, -0.99999994f);
  float e = 1.41421356f * erfinv_xla(u);
  float zv = e * expf(0.5f * lv[i]) + mu[i];
  zf[i] = zv;
  zb[i] = (bf16_t)zv;
}

// ---------------- host ----------------
extern "C" void kernel_launch(void* const* d_in, const int* in_sizes, int n_in,
                              void* d_out, int out_size, void* d_ws, size_t ws_size,
                              hipStream_t stream) {
  const float* x     = (const float*)d_in[0];
  const int*   lens  = (const int*)d_in[1];
  const float* ln_w  = (const float*)d_in[2];
  const float* ln_b  = (const float*)d_in[3];
  const float* enc_w = (const float*)d_in[4];
  const float* enc_b = (const float*)d_in[5];
  const float* Wih_f = (const float*)d_in[6];
  const float* Whh_f = (const float*)d_in[7];
  const float* bih_f = (const float*)d_in[8];
  const float* bhh_f = (const float*)d_in[9];
  const float* Wih_b = (const float*)d_in[10];
  const float* Whh_b = (const float*)d_in[11];
  const float* bih_b = (const float*)d_in[12];
  const float* bhh_b = (const float*)d_in[13];
  const float* mu1_w = (const float*)d_in[14];
  const float* mu1_b = (const float*)d_in[15];
  const float* mu2_w = (const float*)d_in[16];
  const float* mu2_b = (const float*)d_in[17];
  const float* lv1_w = (const float*)d_in[18];
  const float* lv1_b = (const float*)d_in[19];
  const float* lv2_w = (const float*)d_in[20];
  const float* lv2_b = (const float*)d_in[21];
  const float* dz_w  = (const float*)d_in[22];
  const float* dz_b  = (const float*)d_in[23];
  const float* p1_w  = (const float*)d_in[24];
  const float* p1_b  = (const float*)d_in[25];
  const float* p2_w  = (const float*)d_in[26];
  const float* p2_b  = (const float*)d_in[27];
  const float* dWih  = (const float*)d_in[28];
  const float* dWhh  = (const float*)d_in[29];
  const float* dbih  = (const float*)d_in[30];
  const float* dbhh  = (const float*)d_in[31];
  const float* l1_w  = (const float*)d_in[32];
  const float* l1_b  = (const float*)d_in[33];
  const float* l2_w  = (const float*)d_in[34];
  const float* l2_b  = (const float*)d_in[35];

  float* out0    = (float*)d_out;
  float* out_dec = out0 + (long)Bn * Ln * Dn;
  float* out_len = out_dec + (long)Bn * Ln * Dn;
  float* out_mu  = out_len + Bn;
  float* out_lv  = out_mu + (long)Bn * Zn;
  float* out_z   = out_lv + (long)Bn * Zn;

  char* wp = (char*)d_ws;
  auto alloc = [&](size_t bytes) -> void* {
    void* r = (void*)wp;
    wp += (bytes + 255) & ~(size_t)255;
    return r;
  };

  bf16_t* xn      = (bf16_t*)alloc((size_t)Bn * Ln * Dn * 2);
  bf16_t* xs      = (bf16_t*)alloc((size_t)Ln * Bn * Zn * 2);
  bf16_t* encw    = (bf16_t*)alloc((size_t)Zn * Dn * 2);
  bf16_t* mu1b    = (bf16_t*)alloc((size_t)Hn * 2 * Hn * 2);
  bf16_t* lv1b    = (bf16_t*)alloc((size_t)Hn * 2 * Hn * 2);
  bf16_t* mu2b    = (bf16_t*)alloc((size_t)Zn * Hn * 2);
  bf16_t* lv2b    = (bf16_t*)alloc((size_t)Zn * Hn * 2);
  bf16_t* dzb     = (bf16_t*)alloc((size_t)Zn * Zn * 2);
  bf16_t* p1b     = (bf16_t*)alloc((size_t)Zn * Zn * 2);
  bf16_t* p2b     = (bf16_t*)alloc((size_t)Dn * Zn * 2);
  bf16_t* l1b     = (bf16_t*)alloc((size_t)Zn * Hn * 2);
  bf16_t* l2b     = (bf16_t*)alloc((size_t)Dn * Zn * 2);
  bf16_t* pooledb = (bf16_t*)alloc((size_t)Bn * 2 * Hn * 2);
  bf16_t* mu_h    = (bf16_t*)alloc((size_t)Bn * Hn * 2);
  bf16_t* lv_h    = (bf16_t*)alloc((size_t)Bn * Hn * 2);
  bf16_t* zb      = (bf16_t*)alloc((size_t)Bn * Zn * 2);
  bf16_t* xz      = (bf16_t*)alloc((size_t)Bn * Zn * 2);
  bf16_t* t1      = (bf16_t*)alloc((size_t)Bn * Zn * 2);   // init path only
  unsigned* bars  = (unsigned*)alloc(2048);   // enc region [0..255], dec region [256..511]
  unsigned* barE  = bars;
  unsigned* barD  = bars + 256;
  // rings last (big): [Ln+1] slots each
  bf16_t* hringF   = (bf16_t*)alloc((size_t)(Ln + 1) * HSLOT * 2);
  bf16_t* hringB   = (bf16_t*)alloc((size_t)(Ln + 1) * HSLOT * 2);
  bf16_t* hringD   = (bf16_t*)alloc((size_t)(Ln + 1) * HSLOT * 2);
  bf16_t* posering = (bf16_t*)alloc((size_t)(Ln + 1) * PSLOT * 2);

  static int s_attr_done = 0;
  if (!s_attr_done) {
    (void)hipFuncSetAttribute((const void*)k_enc_persist,
                              hipFuncAttributeMaxDynamicSharedMemorySize, ENC_SMEM);
    (void)hipFuncSetAttribute((const void*)k_dec_persist,
                              hipFuncAttributeMaxDynamicSharedMemorySize, DEC_SMEM);
    s_attr_done = 1;
  }

  // zero-init ring slot 0 (initial h state) + barrier state
  hipMemsetAsync(hringF, 0, (size_t)HSLOT * 2, stream);
  hipMemsetAsync(hringB, 0, (size_t)HSLOT * 2, stream);
  hipMemsetAsync(hringD, 0, (size_t)HSLOT * 2, stream);
  hipMemsetAsync(bars, 0, 2048, stream);

  // weight prep for the small GEMMs (bf16 casts), single launch
  k_cast_all<<<2048, 256, 0, stream>>>(enc_w, mu1_w, lv1_w, mu2_w, lv2_w,
                                       dz_w, p1_w, p2_w, l1_w, l2_w,
                                       encw, mu1b, lv1b, mu2b, lv2b,
                                       dzb, p1b, p2b, l1b, l2b);

  // layernorm + x passthrough
  k_layernorm<<<256, 256, 0, stream>>>(x, ln_w, ln_b, out0, xn);

  // encoder input: xs[l][b][:] = relu(xn @ enc_w^T + enc_b)
  k_gemm<1, true><<<dim3(480, 8), 256, 0, stream>>>(xn, Dn, encw, Dn, enc_b,
                                                    nullptr, 0, xs, Zn, Dn);

  // persistent BiLSTM encoder (120 steps, 1 launch)
  {
    void* ea[] = {&xs, &Wih_f, &Whh_f, &bih_f, &bhh_f,
                  &Wih_b, &Whh_b, &bih_b, &bhh_b, &lens,
                  &hringF, &hringB, &pooledb, &out_len, &barE};
    hipLaunchCooperativeKernel((const void*)k_enc_persist, dim3(256), dim3(256),
                               ea, (unsigned)ENC_SMEM, stream);
  }

  // mu / log_var heads
  k_gemm<1, false><<<dim3(4, 16), 256, 0, stream>>>(pooledb, 2 * Hn, mu1b, 2 * Hn, mu1_b,
                                                    nullptr, 0, mu_h, Hn, 2 * Hn);
  k_gemm<1, false><<<dim3(4, 16), 256, 0, stream>>>(pooledb, 2 * Hn, lv1b, 2 * Hn, lv1_b,
                                                    nullptr, 0, lv_h, Hn, 2 * Hn);
  k_gemm<0, false><<<dim3(4, 8), 256, 0, stream>>>(mu_h, Hn, mu2b, Hn, mu2_b,
                                                   out_mu, Zn, nullptr, 0, Hn);
  k_gemm<0, false><<<dim3(4, 8), 256, 0, stream>>>(lv_h, Hn, lv2b, Hn, lv2_b,
                                                   out_lv, Zn, nullptr, 0, Hn);

  // z = eps * exp(0.5 lv) + mu
  k_z<<<512, 256, 0, stream>>>(out_mu, out_lv, out_z, zb);

  // decoder init: xz = relu(z @ dz_w^T); pose0 -> posering slot 0
  k_gemm<1, false><<<dim3(4, 8), 256, 0, stream>>>(zb, Zn, dzb, Zn, dz_b,
                                                   nullptr, 0, xz, Zn, Zn);
  k_gemm<1, false><<<dim3(4, 8), 256, 0, stream>>>(xz, Zn, p1b, Zn, p1_b,
                                                   nullptr, 0, t1, Zn, Zn);
  k_gemm<0, false><<<dim3(4, 3), 256, 0, stream>>>(t1, Zn, p2b, Zn, p2_b,
                                                   nullptr, 0, posering, Dn, Zn);

  // persistent decoder (120 steps x {LSTM, fused l1l2}, 1 launch)
  {
    void* da[] = {&xz, &posering, &dWih, &dWhh, &dbih, &dbhh, &hringD,
                  &l1b, &l1_b, &l2b, &l2_b, &out_dec, &barD};
    hipLaunchCooperativeKernel((const void*)k_dec_persist, dim3(256), dim3(256),
                               da, (unsigned)DEC_SMEM, stream);
  }
}

// Round 11
// 13498.065 us; speedup vs baseline: 1.0340x; 1.0340x over previous
//
#include <hip/hip_runtime.h>

typedef __bf16 bf16_t;
typedef __bf16 bf16x8 __attribute__((ext_vector_type(8)));
typedef __bf16 bf16x4 __attribute__((ext_vector_type(4)));
typedef float  f32x4  __attribute__((ext_vector_type(4)));

#define DEV __device__ __forceinline__

constexpr int Bn = 256;
constexpr int Ln = 120;
constexpr int Dn = 192;
constexpr int Zn = 512;
constexpr int Hn = 1024;          // H = 2*Z
constexpr int KE = Zn + Hn;       // 1536: encoder lstm K  (x | h)
constexpr int KD = Zn + Dn + Hn;  // 1728: decoder lstm K  (xz | pose | h)
constexpr int NBLK = 256;         // persistent grid size
constexpr long HSLOT = (long)Bn * Hn;   // one h ring slot (elements)
constexpr long PSLOT = (long)Bn * Dn;   // one pose ring slot

DEV f32x4 mfma16(bf16x8 a, bf16x8 b, f32x4 c) {
  return __builtin_amdgcn_mfma_f32_16x16x32_bf16(a, b, c, 0, 0, 0);
}
DEV bf16x8 ldb8(const bf16_t* p) { return *reinterpret_cast<const bf16x8*>(p); }
DEV float sigf(float x) { return 1.f / (1.f + expf(-x)); }
DEV unsigned short b2u(bf16_t v) { union { bf16_t b; unsigned short u; } x; x.b = v; return x.u; }

// ---- issue-only coherent loads (sc0 sc1: read from MALL, bypass stale L1/L2).
// NO wait inside: caller retires batches with counted vmcnt (FIFO -> oldest
// batch complete when outstanding drops to the threshold). R4 proved the
// primitive; this round removes its per-batch vmcnt(0) serialization.
DEV void ld4i(const bf16_t* p0, const bf16_t* p1, const bf16_t* p2, const bf16_t* p3,
              bf16x8& o0, bf16x8& o1, bf16x8& o2, bf16x8& o3) {
  asm volatile(
      "global_load_dwordx4 %0, %4, off sc0 sc1\n\t"
      "global_load_dwordx4 %1, %5, off sc0 sc1\n\t"
      "global_load_dwordx4 %2, %6, off sc0 sc1\n\t"
      "global_load_dwordx4 %3, %7, off sc0 sc1"
      : "=&v"(o0), "=&v"(o1), "=&v"(o2), "=&v"(o3)
      : "v"(p0), "v"(p1), "v"(p2), "v"(p3)
      : "memory");
}
DEV void ld8i(const bf16_t* p0, const bf16_t* p1, const bf16_t* p2, const bf16_t* p3,
              const bf16_t* p4, const bf16_t* p5, const bf16_t* p6, const bf16_t* p7,
              bf16x8& o0, bf16x8& o1, bf16x8& o2, bf16x8& o3,
              bf16x8& o4, bf16x8& o5, bf16x8& o6, bf16x8& o7) {
  asm volatile(
      "global_load_dwordx4 %0, %8, off sc0 sc1\n\t"
      "global_load_dwordx4 %1, %9, off sc0 sc1\n\t"
      "global_load_dwordx4 %2, %10, off sc0 sc1\n\t"
      "global_load_dwordx4 %3, %11, off sc0 sc1\n\t"
      "global_load_dwordx4 %4, %12, off sc0 sc1\n\t"
      "global_load_dwordx4 %5, %13, off sc0 sc1\n\t"
      "global_load_dwordx4 %6, %14, off sc0 sc1\n\t"
      "global_load_dwordx4 %7, %15, off sc0 sc1"
      : "=&v"(o0), "=&v"(o1), "=&v"(o2), "=&v"(o3),
        "=&v"(o4), "=&v"(o5), "=&v"(o6), "=&v"(o7)
      : "v"(p0), "v"(p1), "v"(p2), "v"(p3), "v"(p4), "v"(p5), "v"(p6), "v"(p7)
      : "memory");
}
// counted waits + sched fence (rule #18: stop MFMA hoisting past the wait)
#define VW16 do { asm volatile("s_waitcnt vmcnt(16)" ::: "memory"); \
                  __builtin_amdgcn_sched_barrier(0); } while (0)
#define VW8  do { asm volatile("s_waitcnt vmcnt(8)"  ::: "memory"); \
                  __builtin_amdgcn_sched_barrier(0); } while (0)
#define VW0  do { asm volatile("s_waitcnt vmcnt(0)"  ::: "memory"); \
                  __builtin_amdgcn_sched_barrier(0); } while (0)

// ---- coherent stores: write-through to MALL (coherence point) ----
DEV void st16c(bf16_t* p, bf16x8 v) {
  asm volatile("global_store_dwordx4 %0, %1, off sc0 sc1" :: "v"(p), "v"(v) : "memory");
}
DEV void st8c(bf16_t* p, bf16x4 v) {
  asm volatile("global_store_dwordx2 %0, %1, off sc0 sc1" :: "v"(p), "v"(v) : "memory");
}
DEV void st2c(bf16_t* p, unsigned short v) {
  asm volatile("global_store_short %0, %1, off sc0 sc1" :: "v"(p), "v"(v) : "memory");
}

// ---- grid barrier: pure relaxed, distributed arrive (R4-proven) ----
DEV void gbar(unsigned* bar, unsigned epoch, int bid) {
  asm volatile("s_waitcnt vmcnt(0)" ::: "memory");  // drain this wave's sc1 stores
  __syncthreads();                                  // all waves drained + arrived
  if (threadIdx.x == 0) {
    int g = bid & 7;                                // 32 blocks per group
    unsigned a = __hip_atomic_fetch_add(bar + g * 16, 1u, __ATOMIC_RELAXED,
                                        __HIP_MEMORY_SCOPE_AGENT);
    if (a == epoch * 32u - 1u) {
      unsigned b = __hip_atomic_fetch_add(bar + 128, 1u, __ATOMIC_RELAXED,
                                          __HIP_MEMORY_SCOPE_AGENT);
      if (b == epoch * 8u - 1u)
        __hip_atomic_store(bar + 192, epoch, __ATOMIC_RELAXED, __HIP_MEMORY_SCOPE_AGENT);
    }
    while (__hip_atomic_load(bar + 192, __ATOMIC_RELAXED, __HIP_MEMORY_SCOPE_AGENT) < epoch)
      __builtin_amdgcn_s_sleep(2);
  }
  __syncthreads();
}

// ---------------- merged weight-cast kernel (f32 -> bf16, 10 tensors) ----------------
__global__ void k_cast_all(
    const float* __restrict__ s0, const float* __restrict__ s1,
    const float* __restrict__ s2, const float* __restrict__ s3,
    const float* __restrict__ s4, const float* __restrict__ s5,
    const float* __restrict__ s6, const float* __restrict__ s7,
    const float* __restrict__ s8, const float* __restrict__ s9,
    bf16_t* __restrict__ d0, bf16_t* __restrict__ d1,
    bf16_t* __restrict__ d2, bf16_t* __restrict__ d3,
    bf16_t* __restrict__ d4, bf16_t* __restrict__ d5,
    bf16_t* __restrict__ d6, bf16_t* __restrict__ d7,
    bf16_t* __restrict__ d8, bf16_t* __restrict__ d9) {
  const long TOT = 1646592;  // total float4 groups
  for (long gidx = blockIdx.x * blockDim.x + threadIdx.x; gidx < TOT;
       gidx += (long)gridDim.x * blockDim.x) {
    const float* s; bf16_t* d; long r = gidx;
    if      (r < 24576)                      { s = s0; d = d0; }
    else if ((r -= 24576)   < 524288)        { s = s1; d = d1; }
    else if ((r -= 524288)  < 524288)        { s = s2; d = d2; }
    else if ((r -= 524288)  < 131072)        { s = s3; d = d3; }
    else if ((r -= 131072)  < 131072)        { s = s4; d = d4; }
    else if ((r -= 131072)  < 65536)         { s = s5; d = d5; }
    else if ((r -= 65536)   < 65536)         { s = s6; d = d6; }
    else if ((r -= 65536)   < 24576)         { s = s7; d = d7; }
    else if ((r -= 24576)   < 131072)        { s = s8; d = d8; }
    else    { r -= 131072;                     s = s9; d = d9; }
    float4 v = reinterpret_cast<const float4*>(s)[r];
    bf16x4 o;
    o[0] = (bf16_t)v.x; o[1] = (bf16_t)v.y; o[2] = (bf16_t)v.z; o[3] = (bf16_t)v.w;
    *reinterpret_cast<bf16x4*>(d + 4 * r) = o;
  }
}

// ---------------- layernorm over (L,D) per sample + x passthrough ----------------
__global__ void k_layernorm(const float* __restrict__ x, const float* __restrict__ w,
                            const float* __restrict__ bsh, float* __restrict__ out0,
                            bf16_t* __restrict__ xn) {
  const int n = Ln * Dn;  // 23040
  int b = blockIdx.x;
  const float* xb = x + (long)b * n;
  float s = 0.f, s2 = 0.f;
  for (int i = threadIdx.x; i < n; i += 256) { float v = xb[i]; s += v; s2 += v * v; }
  for (int off = 32; off; off >>= 1) { s += __shfl_down(s, off); s2 += __shfl_down(s2, off); }
  __shared__ float sh[8];
  int wave = threadIdx.x >> 6, lane = threadIdx.x & 63;
  if (lane == 0) { sh[wave] = s; sh[4 + wave] = s2; }
  __syncthreads();
  if (threadIdx.x == 0) {
    float S = sh[0] + sh[1] + sh[2] + sh[3];
    float S2 = sh[4] + sh[5] + sh[6] + sh[7];
    float m = S / n;
    float var = fmaxf(S2 / n - m * m, 0.f);
    sh[0] = m; sh[1] = rsqrtf(var + 1e-5f);
  }
  __syncthreads();
  float m = sh[0], inv = sh[1];
  for (int i = threadIdx.x; i < n; i += 256) {
    float v = xb[i];
    out0[(long)b * n + i] = v;
    xn[(long)b * n + i] = (bf16_t)((v - m) * inv * w[i] + bsh[i]);
  }
}

// ---------------- generic bf16 MFMA GEMM: out = act(A @ W^T + bias) ----------------
template <int ACT, bool XSPERM>
__global__ __launch_bounds__(256) void k_gemm(
    const bf16_t* __restrict__ A, int lda,
    const bf16_t* __restrict__ W, int ldw,
    const float* __restrict__ bias,
    float* __restrict__ outF, long ldoF,
    bf16_t* __restrict__ outB, int ldoB,
    int K) {
  int lane = threadIdx.x & 63, wave = threadIdx.x >> 6;
  int l15 = lane & 15, q = lane >> 4;
  int m0 = blockIdx.x * 64 + (wave >> 1) * 32;
  int n0 = blockIdx.y * 64 + (wave & 1) * 32;
  f32x4 acc00 = {}, acc01 = {}, acc10 = {}, acc11 = {};
  const bf16_t* Ap = A + (long)(m0 + l15) * lda + q * 8;
  const bf16_t* Wp = W + (long)(n0 + l15) * ldw + q * 8;
  long a16 = (long)16 * lda, w16 = (long)16 * ldw;
  for (int k0 = 0; k0 < K; k0 += 32) {
    bf16x8 a0 = ldb8(Ap + k0);
    bf16x8 a1 = ldb8(Ap + a16 + k0);
    bf16x8 b0 = ldb8(Wp + k0);
    bf16x8 b1 = ldb8(Wp + w16 + k0);
    acc00 = mfma16(a0, b0, acc00);
    acc01 = mfma16(a0, b1, acc01);
    acc10 = mfma16(a1, b0, acc10);
    acc11 = mfma16(a1, b1, acc11);
  }
#pragma unroll
  for (int mi = 0; mi < 2; ++mi)
#pragma unroll
    for (int ni = 0; ni < 2; ++ni) {
      f32x4 acc = (mi == 0) ? (ni == 0 ? acc00 : acc01) : (ni == 0 ? acc10 : acc11);
#pragma unroll
      for (int r = 0; r < 4; ++r) {
        int m = m0 + mi * 16 + q * 4 + r;
        int nn = n0 + ni * 16 + l15;
        float v = acc[r] + bias[nn];
        if (ACT == 1) v = fmaxf(v, 0.f);
        if (outF) outF[(long)m * ldoF + nn] = v;
        if (outB) {
          long row = XSPERM ? ((long)(m % Ln) * Bn + m / Ln) : m;
          outB[row * (long)ldoB + nn] = (bf16_t)v;
        }
      }
    }
}

// ================= persistent encoder BiLSTM (h ring, pipelined loads) =================
constexpr int ENC_CH = KE / 32;                          // 48 k-chunks
constexpr int ENC_SMEM_W = 2 * ENC_CH * 64 * 16;         // 98304 B
constexpr int ENC_SMEM_G = 4 * 64 * 33 * 4;              // 33792 B gate buffers
constexpr int ENC_SMEM = ENC_SMEM_W + ENC_SMEM_G + 128;  // 132224 B

__global__ __launch_bounds__(256, 1) void k_enc_persist(
    const bf16_t* __restrict__ xs,   // [L][B][Z]
    const float* __restrict__ WihF, const float* __restrict__ WhhF,
    const float* __restrict__ bihF, const float* __restrict__ bhhF,
    const float* __restrict__ WihB, const float* __restrict__ WhhB,
    const float* __restrict__ bihB, const float* __restrict__ bhhB,
    const int* __restrict__ lens,
    bf16_t* __restrict__ hringF,     // [Ln+1][B][H] ring, slot 0 zeroed
    bf16_t* __restrict__ hringB,
    bf16_t* __restrict__ pooledb, float* __restrict__ out_len,
    unsigned* bar) {
  extern __shared__ char smem[];
  bf16x8* Wl = (bf16x8*)smem;
  float* Gbuf = (float*)(smem + ENC_SMEM_W);
  float* bias_l = (float*)(smem + ENC_SMEM_W + ENC_SMEM_G);

  int bid = blockIdx.x;
  int dir = bid >> 7;
  int j0 = (bid & 127) * 8;
  const float* Wih = dir ? WihB : WihF;
  const float* Whh = dir ? WhhB : WhhF;
  const float* bih = dir ? bihB : bihF;
  const float* bhh = dir ? bhhB : bhhF;
  bf16_t* hring = dir ? hringB : hringF;

  int tid = threadIdx.x;
  // ---- stage weight slice into LDS (fragment-major), f32 -> bf16 on the fly
  for (int f = tid; f < 2 * ENC_CH * 64; f += 256) {
    int ni = f / (ENC_CH * 64);
    int rem = f - ni * (ENC_CH * 64);
    int c = rem >> 6, sub = rem & 63;
    int sl = sub & 15, sq = sub >> 4;
    int r = ni * 16 + sl;                      // local W row 0..31
    int grow = (r >> 3) * Hn + j0 + (r & 7);   // global row: gate*H + col
    int k = c * 32 + sq * 8;
    const float* src = (k < Zn) ? (Wih + (long)grow * Zn + k)
                                : (Whh + (long)grow * Hn + (k - Zn));
    bf16x8 v;
#pragma unroll
    for (int e = 0; e < 8; ++e) v[e] = (bf16_t)src[e];
    Wl[f] = v;
  }
  if (tid < 32) {
    int grow = (tid >> 3) * Hn + j0 + (tid & 7);
    bias_l[tid] = bih[grow] + bhh[grow];
  }
  if (bid == 0) out_len[tid] = (float)lens[tid];
  __syncthreads();

  int wave = tid >> 6, lane = tid & 63;
  int l15 = lane & 15, q = lane >> 4;
  int mrow = wave * 64 + l15;      // + mi*16 -> A-frag rows
  int m = wave * 64 + lane;        // pointwise: this thread owns batch row m
  int mylen = lens[m];
  float c_reg[8] = {}, h_reg[8] = {}, pool_reg[8] = {};
  float* Gw = Gbuf + wave * (64 * 33);
  const bf16x8* Wl0 = Wl;
  const bf16x8* Wl1 = Wl + ENC_CH * 64;
  const long h16 = (long)16 * Hn;

#define ENC_HISS(A, c) do { long hk_ = (long)(c) * 32 - Zn;                               \
    ld8i(hrow + hk_,            hrow + h16 + hk_,                                         \
         hrow + 2 * h16 + hk_,  hrow + 3 * h16 + hk_,                                     \
         hrow + hk_ + 32,       hrow + h16 + hk_ + 32,                                    \
         hrow + 2 * h16 + hk_ + 32, hrow + 3 * h16 + hk_ + 32,                            \
         A[0], A[1], A[2], A[3], A[4], A[5], A[6], A[7]); } while (0)
#define ENC_HCONS(A, c) do {                                                              \
    { bf16x8 b0 = Wl0[(c) * 64 + lane], b1 = Wl1[(c) * 64 + lane];                        \
      acc[0][0] = mfma16(A[0], b0, acc[0][0]); acc[0][1] = mfma16(A[0], b1, acc[0][1]);   \
      acc[1][0] = mfma16(A[1], b0, acc[1][0]); acc[1][1] = mfma16(A[1], b1, acc[1][1]);   \
      acc[2][0] = mfma16(A[2], b0, acc[2][0]); acc[2][1] = mfma16(A[2], b1, acc[2][1]);   \
      acc[3][0] = mfma16(A[3], b0, acc[3][0]); acc[3][1] = mfma16(A[3], b1, acc[3][1]); } \
    { bf16x8 b0 = Wl0[((c) + 1) * 64 + lane], b1 = Wl1[((c) + 1) * 64 + lane];            \
      acc[0][0] = mfma16(A[4], b0, acc[0][0]); acc[0][1] = mfma16(A[4], b1, acc[0][1]);   \
      acc[1][0] = mfma16(A[5], b0, acc[1][0]); acc[1][1] = mfma16(A[5], b1, acc[1][1]);   \
      acc[2][0] = mfma16(A[6], b0, acc[2][0]); acc[2][1] = mfma16(A[6], b1, acc[2][1]);   \
      acc[3][0] = mfma16(A[7], b0, acc[3][0]); acc[3][1] = mfma16(A[7], b1, acc[3][1]); } \
  } while (0)

  for (int t = 0; t < Ln; ++t) {
    int tt = dir ? (Ln - 1 - t) : t;
    const bf16_t* xt = xs + (long)tt * Bn * Zn;
    const bf16_t* hprev = hring + (long)t * HSLOT;        // MALL read (sc0sc1)
    bf16_t* hcur = hring + (long)(t + 1) * HSLOT;         // write-through

    f32x4 acc[4][2] = {};
    const bf16_t* xrow = xt + (long)mrow * Zn + q * 8;
    const bf16_t* hrow = hprev + (long)mrow * Hn + q * 8;
    // x part: plain cached loads (immutable), compiler-managed
    for (int c = 0; c < Zn / 32; ++c) {
      bf16x8 b0 = Wl0[c * 64 + lane];
      bf16x8 b1 = Wl1[c * 64 + lane];
#pragma unroll
      for (int mi = 0; mi < 4; ++mi) {
        bf16x8 a = ldb8(xrow + (long)mi * 16 * Zn + c * 32);
        acc[mi][0] = mfma16(a, b0, acc[mi][0]);
        acc[mi][1] = mfma16(a, b1, acc[mi][1]);
      }
    }
    // h part: 16 batches of 8 sc0sc1 loads, 3 deep, counted-vmcnt retirement
    {
      bf16x8 HA[8], HB[8], HC[8];
      ENC_HISS(HA, 16); ENC_HISS(HB, 18); ENC_HISS(HC, 20);
      VW16; ENC_HCONS(HA, 16); ENC_HISS(HA, 22);
      VW16; ENC_HCONS(HB, 18); ENC_HISS(HB, 24);
      VW16; ENC_HCONS(HC, 20); ENC_HISS(HC, 26);
      VW16; ENC_HCONS(HA, 22); ENC_HISS(HA, 28);
      VW16; ENC_HCONS(HB, 24); ENC_HISS(HB, 30);
      VW16; ENC_HCONS(HC, 26); ENC_HISS(HC, 32);
      VW16; ENC_HCONS(HA, 28); ENC_HISS(HA, 34);
      VW16; ENC_HCONS(HB, 30); ENC_HISS(HB, 36);
      VW16; ENC_HCONS(HC, 32); ENC_HISS(HC, 38);
      VW16; ENC_HCONS(HA, 34); ENC_HISS(HA, 40);
      VW16; ENC_HCONS(HB, 36); ENC_HISS(HB, 42);
      VW16; ENC_HCONS(HC, 38); ENC_HISS(HC, 44);
      VW16; ENC_HCONS(HA, 40); ENC_HISS(HA, 46);
      VW16; ENC_HCONS(HB, 42);
      VW8;  ENC_HCONS(HC, 44);
      VW0;  ENC_HCONS(HA, 46);
    }
    // dump gates to wave-private LDS (row = m-local, col = gate*8 + j-local)
#pragma unroll
    for (int mi = 0; mi < 4; ++mi)
#pragma unroll
      for (int ni = 0; ni < 2; ++ni)
#pragma unroll
        for (int r = 0; r < 4; ++r)
          Gw[(mi * 16 + q * 4 + r) * 33 + ni * 16 + l15] = acc[mi][ni][r];
    __syncthreads();
    bool act = tt < mylen;
    const float* Gr = Gw + lane * 33;
    bf16x8 hpack;
#pragma unroll
    for (int jj = 0; jj < 8; ++jj) {
      float Gi = Gr[jj] + bias_l[jj];
      float Gf = Gr[8 + jj] + bias_l[8 + jj];
      float Gg = Gr[16 + jj] + bias_l[16 + jj];
      float Go = Gr[24 + jj] + bias_l[24 + jj];
      float cn = sigf(Gf) * c_reg[jj] + sigf(Gi) * tanhf(Gg);
      float hn = sigf(Go) * tanhf(cn);
      if (act) { c_reg[jj] = cn; h_reg[jj] = hn; pool_reg[jj] += hn; }
      hpack[jj] = (bf16_t)h_reg[jj];
    }
    st16c(hcur + (long)m * Hn + j0, hpack);
    if (t != Ln - 1) gbar(bar, (unsigned)(t + 1), bid);
  }
#undef ENC_HCONS
#undef ENC_HISS
  // pooled / len  (bf16 for the mu/lv heads; kernel boundary handles coherence)
  bf16x8 pp;
#pragma unroll
  for (int jj = 0; jj < 8; ++jj) pp[jj] = (bf16_t)(pool_reg[jj] / (float)mylen);
  *(bf16x8*)(pooledb + (long)m * (2 * Hn) + dir * Hn + j0) = pp;
}

// ============ persistent decoder: LSTM + fused l1l2, rings, pipelined loads ============
constexpr int DEC_CH = KD / 32;                          // 54 k-chunks
constexpr int DEC_SMEM_W = 2 * DEC_CH * 64 * 16;         // 110592 B
constexpr int DEC_SMEM_G = 4 * 32 * 33 * 4;              // 16896 B (also reused as t1 tile)
constexpr int DEC_SMEM = DEC_SMEM_W + DEC_SMEM_G + 128;  // 127616 B

__global__ __launch_bounds__(256, 1) void k_dec_persist(
    const bf16_t* __restrict__ xz,   // [B][Zn] immutable
    bf16_t* __restrict__ posering,   // [Ln+1][B][Dn] ring, slot 0 = pose0
    const float* __restrict__ dWih, const float* __restrict__ dWhh,
    const float* __restrict__ dbih, const float* __restrict__ dbhh,
    bf16_t* __restrict__ hring,      // [Ln+1][B][H] ring, slot 0 zeroed
    const bf16_t* __restrict__ l1w, const float* __restrict__ l1bias,
    const bf16_t* __restrict__ l2w, const float* __restrict__ l2bias,
    float* __restrict__ out_dec,
    unsigned* bar) {
  extern __shared__ char smem[];
  bf16x8* Wl = (bf16x8*)smem;
  float* Gbuf = (float*)(smem + DEC_SMEM_W);
  float* bias_l = (float*)(smem + DEC_SMEM_W + DEC_SMEM_G);

  int bid = blockIdx.x;
  int mbase = (bid >> 7) * 128;
  int j0 = (bid & 127) * 8;
  int tid = threadIdx.x;

  for (int f = tid; f < 2 * DEC_CH * 64; f += 256) {
    int ni = f / (DEC_CH * 64);
    int rem = f - ni * (DEC_CH * 64);
    int c = rem >> 6, sub = rem & 63;
    int sl = sub & 15, sq = sub >> 4;
    int r = ni * 16 + sl;
    int grow = (r >> 3) * Hn + j0 + (r & 7);
    int k = c * 32 + sq * 8;
    // K layout: [0,Zn)=xz, [Zn,Zn+Dn)=pose, [Zn+Dn,KD)=h
    const float* src = (k < Zn + Dn) ? (dWih + (long)grow * (Zn + Dn) + k)
                                     : (dWhh + (long)grow * Hn + (k - (Zn + Dn)));
    bf16x8 v;
#pragma unroll
    for (int e = 0; e < 8; ++e) v[e] = (bf16_t)src[e];
    Wl[f] = v;
  }
  if (tid < 32) {
    int grow = (tid >> 3) * Hn + j0 + (tid & 7);
    bias_l[tid] = dbih[grow] + dbhh[grow];
  }
  __syncthreads();

  int wave = tid >> 6, lane = tid & 63;
  int l15 = lane & 15, q = lane >> 4;
  int mrow = mbase + wave * 32 + l15;          // + mi*16
  int mpt = mbase + wave * 32 + (lane >> 1);   // pointwise m
  int jh = (lane & 1) * 4;                     // pointwise j-half
  float c_reg[4] = {};
  float* Gw = Gbuf + wave * (32 * 33);
  const bf16x8* Wl0 = Wl;
  const bf16x8* Wl1 = Wl + DEC_CH * 64;
  const long h16d = (long)16 * Hn;
  const long i16p = (long)16 * Dn;

#define DEC_HISS(A, c) do { long hk_ = (long)(c) * 32 - (Zn + Dn);                        \
    ld8i(hrow + hk_,        hrow + h16d + hk_,                                            \
         hrow + hk_ + 32,   hrow + h16d + hk_ + 32,                                       \
         hrow + hk_ + 64,   hrow + h16d + hk_ + 64,                                       \
         hrow + hk_ + 96,   hrow + h16d + hk_ + 96,                                       \
         A[0], A[1], A[2], A[3], A[4], A[5], A[6], A[7]); } while (0)
#define DEC_HCONS(A, c) do {                                                              \
    { bf16x8 b0 = Wl0[(c) * 64 + lane], b1 = Wl1[(c) * 64 + lane];                        \
      acc[0][0] = mfma16(A[0], b0, acc[0][0]); acc[0][1] = mfma16(A[0], b1, acc[0][1]);   \
      acc[1][0] = mfma16(A[1], b0, acc[1][0]); acc[1][1] = mfma16(A[1], b1, acc[1][1]); } \
    { bf16x8 b0 = Wl0[((c) + 1) * 64 + lane], b1 = Wl1[((c) + 1) * 64 + lane];            \
      acc[0][0] = mfma16(A[2], b0, acc[0][0]); acc[0][1] = mfma16(A[2], b1, acc[0][1]);   \
      acc[1][0] = mfma16(A[3], b0, acc[1][0]); acc[1][1] = mfma16(A[3], b1, acc[1][1]); } \
    { bf16x8 b0 = Wl0[((c) + 2) * 64 + lane], b1 = Wl1[((c) + 2) * 64 + lane];            \
      acc[0][0] = mfma16(A[4], b0, acc[0][0]); acc[0][1] = mfma16(A[4], b1, acc[0][1]);   \
      acc[1][0] = mfma16(A[5], b0, acc[1][0]); acc[1][1] = mfma16(A[5], b1, acc[1][1]); } \
    { bf16x8 b0 = Wl0[((c) + 3) * 64 + lane], b1 = Wl1[((c) + 3) * 64 + lane];            \
      acc[0][0] = mfma16(A[6], b0, acc[0][0]); acc[0][1] = mfma16(A[6], b1, acc[0][1]);   \
      acc[1][0] = mfma16(A[7], b0, acc[1][0]); acc[1][1] = mfma16(A[7], b1, acc[1][1]); } \
  } while (0)

  for (int t = 0; t < Ln; ++t) {
    const bf16_t* hprev = hring + (long)t * HSLOT;
    bf16_t* hcur = hring + (long)(t + 1) * HSLOT;
    const bf16_t* poset = posering + (long)t * PSLOT;
    bf16_t* posen = posering + (long)(t + 1) * PSLOT;

    // ---- phase 1: LSTM gates + pointwise
    f32x4 acc[2][2] = {};
    const bf16_t* xrow = xz + (long)mrow * Zn + q * 8;
    const bf16_t* prow = poset + (long)mrow * Dn + q * 8;
    const bf16_t* hrow = hprev + (long)mrow * Hn + q * 8;
    // xz: plain cached (immutable), compiler-managed; completes before pipeline
    for (int c = 0; c < Zn / 32; ++c) {
      bf16x8 b0 = Wl0[c * 64 + lane];
      bf16x8 b1 = Wl1[c * 64 + lane];
#pragma unroll
      for (int mi = 0; mi < 2; ++mi) {
        bf16x8 a = ldb8(xrow + (long)mi * 16 * Zn + c * 32);
        acc[mi][0] = mfma16(a, b0, acc[mi][0]);
        acc[mi][1] = mfma16(a, b1, acc[mi][1]);
      }
    }
    // pose (12 loads) + h (8 batches of 8), 3 deep, counted-vmcnt
    {
      bf16x8 P0, P1, P2, P3, P4, P5, P6, P7, P8, P9, P10, P11;
      bf16x8 HA[8], HB[8], HC[8];
      ld8i(prow,       prow + i16p,       prow + 32, prow + i16p + 32,
           prow + 64,  prow + i16p + 64,  prow + 96, prow + i16p + 96,
           P0, P1, P2, P3, P4, P5, P6, P7);
      ld4i(prow + 128, prow + i16p + 128, prow + 160, prow + i16p + 160,
           P8, P9, P10, P11);
      DEC_HISS(HA, 22); DEC_HISS(HB, 26);
      VW16;  // 28 outstanding -> 16: pose batch (12) retired
      { bf16x8 b0 = Wl0[16 * 64 + lane], b1 = Wl1[16 * 64 + lane];
        acc[0][0] = mfma16(P0, b0, acc[0][0]); acc[0][1] = mfma16(P0, b1, acc[0][1]);
        acc[1][0] = mfma16(P1, b0, acc[1][0]); acc[1][1] = mfma16(P1, b1, acc[1][1]); }
      { bf16x8 b0 = Wl0[17 * 64 + lane], b1 = Wl1[17 * 64 + lane];
        acc[0][0] = mfma16(P2, b0, acc[0][0]); acc[0][1] = mfma16(P2, b1, acc[0][1]);
        acc[1][0] = mfma16(P3, b0, acc[1][0]); acc[1][1] = mfma16(P3, b1, acc[1][1]); }
      { bf16x8 b0 = Wl0[18 * 64 + lane], b1 = Wl1[18 * 64 + lane];
        acc[0][0] = mfma16(P4, b0, acc[0][0]); acc[0][1] = mfma16(P4, b1, acc[0][1]);
        acc[1][0] = mfma16(P5, b0, acc[1][0]); acc[1][1] = mfma16(P5, b1, acc[1][1]); }
      { bf16x8 b0 = Wl0[19 * 64 + lane], b1 = Wl1[19 * 64 + lane];
        acc[0][0] = mfma16(P6, b0, acc[0][0]); acc[0][1] = mfma16(P6, b1, acc[0][1]);
        acc[1][0] = mfma16(P7, b0, acc[1][0]); acc[1][1] = mfma16(P7, b1, acc[1][1]); }
      { bf16x8 b0 = Wl0[20 * 64 + lane], b1 = Wl1[20 * 64 + lane];
        acc[0][0] = mfma16(P8, b0, acc[0][0]); acc[0][1] = mfma16(P8, b1, acc[0][1]);
        acc[1][0] = mfma16(P9, b0, acc[1][0]); acc[1][1] = mfma16(P9, b1, acc[1][1]); }
      { bf16x8 b0 = Wl0[21 * 64 + lane], b1 = Wl1[21 * 64 + lane];
        acc[0][0] = mfma16(P10, b0, acc[0][0]); acc[0][1] = mfma16(P10, b1, acc[0][1]);
        acc[1][0] = mfma16(P11, b0, acc[1][0]); acc[1][1] = mfma16(P11, b1, acc[1][1]); }
      DEC_HISS(HC, 30);
      VW16; DEC_HCONS(HA, 22); DEC_HISS(HA, 34);
      VW16; DEC_HCONS(HB, 26); DEC_HISS(HB, 38);
      VW16; DEC_HCONS(HC, 30); DEC_HISS(HC, 42);
      VW16; DEC_HCONS(HA, 34); DEC_HISS(HA, 46);
      VW16; DEC_HCONS(HB, 38); DEC_HISS(HB, 50);
      VW16; DEC_HCONS(HC, 42);
      VW8;  DEC_HCONS(HA, 46);
      VW0;  DEC_HCONS(HB, 50);
    }
#pragma unroll
    for (int mi = 0; mi < 2; ++mi)
#pragma unroll
      for (int ni = 0; ni < 2; ++ni)
#pragma unroll
        for (int r = 0; r < 4; ++r)
          Gw[(mi * 16 + q * 4 + r) * 33 + ni * 16 + l15] = acc[mi][ni][r];
    __syncthreads();
    {
      const float* Gr = Gw + (lane >> 1) * 33 + jh;
      bf16x4 hp;
#pragma unroll
      for (int p = 0; p < 4; ++p) {
        float Gi = Gr[p] + bias_l[jh + p];
        float Gf = Gr[8 + p] + bias_l[8 + jh + p];
        float Gg = Gr[16 + p] + bias_l[16 + jh + p];
        float Go = Gr[24 + p] + bias_l[24 + jh + p];
        float cn = sigf(Gf) * c_reg[p] + sigf(Gi) * tanhf(Gg);
        c_reg[p] = cn;
        hp[p] = (bf16_t)(sigf(Go) * tanhf(cn));
      }
      st8c(hcur + (long)mpt * Hn + j0 + jh, hp);
    }
    gbar(bar, (unsigned)(2 * t + 1), bid);

    // ---- phase 2 (fused l1+l2): blocks 0..15 each own 16 batch rows.
    if (bid < 16) {
      int r0 = bid * 16;
      f32x4 accl[8] = {};
      const bf16_t* ha = hcur + (long)(r0 + l15) * Hn + q * 8;
      const bf16_t* wb1 = l1w + (long)(wave * 128 + l15) * Hn + q * 8;
      bf16x8 QA[8], QB[8], QC[8], QD[8];
#define Q_ISS(A, c0) ld8i(ha + ((c0) + 0) * 32, ha + ((c0) + 1) * 32,                     \
                          ha + ((c0) + 2) * 32, ha + ((c0) + 3) * 32,                     \
                          ha + ((c0) + 4) * 32, ha + ((c0) + 5) * 32,                     \
                          ha + ((c0) + 6) * 32, ha + ((c0) + 7) * 32,                     \
                          A[0], A[1], A[2], A[3], A[4], A[5], A[6], A[7])
#define Q_CONS(A, c0) do {                                                                \
    for (int k_ = 0; k_ < 8; ++k_) {                                                      \
      _Pragma("unroll")                                                                   \
      for (int nti = 0; nti < 8; ++nti)                                                   \
        accl[nti] = mfma16(A[k_], ldb8(wb1 + (long)nti * 16 * Hn + ((c0) + k_) * 32),     \
                           accl[nti]);                                                    \
    } } while (0)
      Q_ISS(QA, 0); Q_ISS(QB, 8); Q_ISS(QC, 16);
      VW16; Q_CONS(QA, 0); Q_ISS(QD, 24);
      VW16; Q_CONS(QB, 8);
      VW8;  Q_CONS(QC, 16);
      VW0;  Q_CONS(QD, 24);
#undef Q_CONS
#undef Q_ISS
      bf16_t* t1l = (bf16_t*)Gbuf;               // [16][520] bf16 tile
#pragma unroll
      for (int nti = 0; nti < 8; ++nti) {
        int n = wave * 128 + nti * 16 + l15;
        float bb = l1bias[n];
#pragma unroll
        for (int r = 0; r < 4; ++r)
          t1l[(q * 4 + r) * 520 + n] = (bf16_t)fmaxf(accl[nti][r] + bb, 0.f);
      }
      __syncthreads();                           // block-local: t1 tile ready
      f32x4 acc2[3] = {};
      const bf16_t* ta = t1l + l15 * 520 + q * 8;
      const bf16_t* wb2 = l2w + (long)(wave * 48 + l15) * Zn + q * 8;
      for (int c = 0; c < Zn / 32; ++c) {
        bf16x8 a = *reinterpret_cast<const bf16x8*>(ta + c * 32);
#pragma unroll
        for (int i = 0; i < 3; ++i) {
          bf16x8 b = ldb8(wb2 + (long)i * 16 * Zn + c * 32);
          acc2[i] = mfma16(a, b, acc2[i]);
        }
      }
#pragma unroll
      for (int i = 0; i < 3; ++i) {
        int n = wave * 48 + i * 16 + l15;
        float bb = l2bias[n];
#pragma unroll
        for (int r = 0; r < 4; ++r) {
          int mm = r0 + q * 4 + r;
          float v = acc2[i][r] + bb;
          out_dec[(long)mm * (Ln * Dn) + (long)t * Dn + n] = v;
          st2c(posen + (long)mm * Dn + n, b2u((bf16_t)v));
        }
      }
    }
    if (t != Ln - 1) gbar(bar, (unsigned)(2 * t + 2), bid);
  }
#undef DEC_HCONS
#undef DEC_HISS
}

// ---------------- z = eps * exp(0.5 lv) + mu ----------------
DEV unsigned rotl32(unsigned v, int s) { return (v << s) | (v >> (32 - s)); }

#define TF_R4(r0, r1, r2, r3)                       \
  x0 += x1; x1 = rotl32(x1, r0); x1 ^= x0;          \
  x0 += x1; x1 = rotl32(x1, r1); x1 ^= x0;          \
  x0 += x1; x1 = rotl32(x1, r2); x1 ^= x0;          \
  x0 += x1; x1 = rotl32(x1, r3); x1 ^= x0;

DEV float erfinv_xla(float x) {
  float w = -log1pf(-x * x);
  float p;
  if (w < 5.f) {
    w -= 2.5f;
    p = 2.81022636e-08f;
    p = fmaf(p, w, 3.43273939e-07f);
    p = fmaf(p, w, -3.5233877e-06f);
    p = fmaf(p, w, -4.39150654e-06f);
    p = fmaf(p, w, 0.00021858087f);
    p = fmaf(p, w, -0.00125372503f);
    p = fmaf(p, w, -0.00417768164f);
    p = fmaf(p, w, 0.246640727f);
    p = fmaf(p, w, 1.50140941f);
  } else {
    w = sqrtf(w) - 3.f;
    p = -0.000200214257f;
    p = fmaf(p, w, 0.000100950558f);
    p = fmaf(p, w, 0.00134934322f);
    p = fmaf(p, w, -0.00367342844f);
    p = fmaf(p, w, 0.00573950773f);
    p = fmaf(p, w, -0.0076224613f);
    p = fmaf(p, w, 0.00943887047f);
    p = fmaf(p, w, 1.00167406f);
    p = fmaf(p, w, 2.83297682f);
  }
  return p * x;
}

__global__ void k_z(const float* __restrict__ mu, const float* __restrict__ lv,
                    float* __restrict__ zf, bf16_t* __restrict__ zb) {
  int i = blockIdx.x * blockDim.x + threadIdx.x;  // 0..131071
  const unsigned ks0 = 0u, ks1 = 42u, ks2 = 0x1BD11BDAu ^ ks0 ^ ks1;
  unsigned x0 = 0u + ks0;
  unsigned x1 = (unsigned)i + ks1;
  TF_R4(13, 15, 26, 6);  x0 += ks1; x1 += ks2 + 1u;
  TF_R4(17, 29, 16, 24); x0 += ks2; x1 += ks0 + 2u;
  TF_R4(13, 15, 26, 6);  x0 += ks0; x1 += ks1 + 3u;
  TF_R4(17, 29, 16, 24); x0 += ks1; x1 += ks2 + 4u;
  TF_R4(13, 15, 26, 6);  x0 += ks2; x1 += ks0 + 5u;
  unsigned bits = x0 ^ x1;
  float f = __uint_as_float((bits >> 9) | 0x3F800000u) - 1.0f;
  float u = f * 2.0f + (-0.99999994f);
  u = fmaxf(u, -0.99999994f);
  float e = 1.41421356f * erfinv_xla(u);
  float zv = e * expf(0.5f * lv[i]) + mu[i];
  zf[i] = zv;
  zb[i] = (bf16_t)zv;
}

// ---------------- host ----------------
extern "C" void kernel_launch(void* const* d_in, const int* in_sizes, int n_in,
                              void* d_out, int out_size, void* d_ws, size_t ws_size,
                              hipStream_t stream) {
  const float* x     = (const float*)d_in[0];
  const int*   lens  = (const int*)d_in[1];
  const float* ln_w  = (const float*)d_in[2];
  const float* ln_b  = (const float*)d_in[3];
  const float* enc_w = (const float*)d_in[4];
  const float* enc_b = (const float*)d_in[5];
  const float* Wih_f = (const float*)d_in[6];
  const float* Whh_f = (const float*)d_in[7];
  const float* bih_f = (const float*)d_in[8];
  const float* bhh_f = (const float*)d_in[9];
  const float* Wih_b = (const float*)d_in[10];
  const float* Whh_b = (const float*)d_in[11];
  const float* bih_b = (const float*)d_in[12];
  const float* bhh_b = (const float*)d_in[13];
  const float* mu1_w = (const float*)d_in[14];
  const float* mu1_b = (const float*)d_in[15];
  const float* mu2_w = (const float*)d_in[16];
  const float* mu2_b = (const float*)d_in[17];
  const float* lv1_w = (const float*)d_in[18];
  const float* lv1_b = (const float*)d_in[19];
  const float* lv2_w = (const float*)d_in[20];
  const float* lv2_b = (const float*)d_in[21];
  const float* dz_w  = (const float*)d_in[22];
  const float* dz_b  = (const float*)d_in[23];
  const float* p1_w  = (const float*)d_in[24];
  const float* p1_b  = (const float*)d_in[25];
  const float* p2_w  = (const float*)d_in[26];
  const float* p2_b  = (const float*)d_in[27];
  const float* dWih  = (const float*)d_in[28];
  const float* dWhh  = (const float*)d_in[29];
  const float* dbih  = (const float*)d_in[30];
  const float* dbhh  = (const float*)d_in[31];
  const float* l1_w  = (const float*)d_in[32];
  const float* l1_b  = (const float*)d_in[33];
  const float* l2_w  = (const float*)d_in[34];
  const float* l2_b  = (const float*)d_in[35];

  float* out0    = (float*)d_out;
  float* out_dec = out0 + (long)Bn * Ln * Dn;
  float* out_len = out_dec + (long)Bn * Ln * Dn;
  float* out_mu  = out_len + Bn;
  float* out_lv  = out_mu + (long)Bn * Zn;
  float* out_z   = out_lv + (long)Bn * Zn;

  char* wp = (char*)d_ws;
  auto alloc = [&](size_t bytes) -> void* {
    void* r = (void*)wp;
    wp += (bytes + 255) & ~(size_t)255;
    return r;
  };

  bf16_t* xn      = (bf16_t*)alloc((size_t)Bn * Ln * Dn * 2);
  bf16_t* xs      = (bf16_t*)alloc((size_t)Ln * Bn * Zn * 2);
  bf16_t* encw    = (bf16_t*)alloc((size_t)Zn * Dn * 2);
  bf16_t* mu1b    = (bf16_t*)alloc((size_t)Hn * 2 * Hn * 2);
  bf16_t* lv1b    = (bf16_t*)alloc((size_t)Hn * 2 * Hn * 2);
  bf16_t* mu2b    = (bf16_t*)alloc((size_t)Zn * Hn * 2);
  bf16_t* lv2b    = (bf16_t*)alloc((size_t)Zn * Hn * 2);
  bf16_t* dzb     = (bf16_t*)alloc((size_t)Zn * Zn * 2);
  bf16_t* p1b     = (bf16_t*)alloc((size_t)Zn * Zn * 2);
  bf16_t* p2b     = (bf16_t*)alloc((size_t)Dn * Zn * 2);
  bf16_t* l1b     = (bf16_t*)alloc((size_t)Zn * Hn * 2);
  bf16_t* l2b     = (bf16_t*)alloc((size_t)Dn * Zn * 2);
  bf16_t* pooledb = (bf16_t*)alloc((size_t)Bn * 2 * Hn * 2);
  bf16_t* mu_h    = (bf16_t*)alloc((size_t)Bn * Hn * 2);
  bf16_t* lv_h    = (bf16_t*)alloc((size_t)Bn * Hn * 2);
  bf16_t* zb      = (bf16_t*)alloc((size_t)Bn * Zn * 2);
  bf16_t* xz      = (bf16_t*)alloc((size_t)Bn * Zn * 2);
  bf16_t* t1      = (bf16_t*)alloc((size_t)Bn * Zn * 2);   // init path only
  unsigned* bars  = (unsigned*)alloc(2048);   // enc region [0..255], dec region [256..511]
  unsigned* barE  = bars;
  unsigned* barD  = bars + 256;
  // rings last (big): [Ln+1] slots each
  bf16_t* hringF   = (bf16_t*)alloc((size_t)(Ln + 1) * HSLOT * 2);
  bf16_t* hringB   = (bf16_t*)alloc((size_t)(Ln + 1) * HSLOT * 2);
  bf16_t* hringD   = (bf16_t*)alloc((size_t)(Ln + 1) * HSLOT * 2);
  bf16_t* posering = (bf16_t*)alloc((size_t)(Ln + 1) * PSLOT * 2);

  static int s_attr_done = 0;
  if (!s_attr_done) {
    (void)hipFuncSetAttribute((const void*)k_enc_persist,
                              hipFuncAttributeMaxDynamicSharedMemorySize, ENC_SMEM);
    (void)hipFuncSetAttribute((const void*)k_dec_persist,
                              hipFuncAttributeMaxDynamicSharedMemorySize, DEC_SMEM);
    s_attr_done = 1;
  }

  // zero-init ring slot 0 (initial h state) + barrier state
  hipMemsetAsync(hringF, 0, (size_t)HSLOT * 2, stream);
  hipMemsetAsync(hringB, 0, (size_t)HSLOT * 2, stream);
  hipMemsetAsync(hringD, 0, (size_t)HSLOT * 2, stream);
  hipMemsetAsync(bars, 0, 2048, stream);

  // weight prep for the small GEMMs (bf16 casts), single launch
  k_cast_all<<<2048, 256, 0, stream>>>(enc_w, mu1_w, lv1_w, mu2_w, lv2_w,
                                       dz_w, p1_w, p2_w, l1_w, l2_w,
                                       encw, mu1b, lv1b, mu2b, lv2b,
                                       dzb, p1b, p2b, l1b, l2b);

  // layernorm + x passthrough
  k_layernorm<<<256, 256, 0, stream>>>(x, ln_w, ln_b, out0, xn);

  // encoder input: xs[l][b][:] = relu(xn @ enc_w^T + enc_b)
  k_gemm<1, true><<<dim3(480, 8), 256, 0, stream>>>(xn, Dn, encw, Dn, enc_b,
                                                    nullptr, 0, xs, Zn, Dn);

  // persistent BiLSTM encoder (120 steps, 1 launch)
  {
    void* ea[] = {&xs, &Wih_f, &Whh_f, &bih_f, &bhh_f,
                  &Wih_b, &Whh_b, &bih_b, &bhh_b, &lens,
                  &hringF, &hringB, &pooledb, &out_len, &barE};
    hipLaunchCooperativeKernel((const void*)k_enc_persist, dim3(256), dim3(256),
                               ea, (unsigned)ENC_SMEM, stream);
  }

  // mu / log_var heads
  k_gemm<1, false><<<dim3(4, 16), 256, 0, stream>>>(pooledb, 2 * Hn, mu1b, 2 * Hn, mu1_b,
                                                    nullptr, 0, mu_h, Hn, 2 * Hn);
  k_gemm<1, false><<<dim3(4, 16), 256, 0, stream>>>(pooledb, 2 * Hn, lv1b, 2 * Hn, lv1_b,
                                                    nullptr, 0, lv_h, Hn, 2 * Hn);
  k_gemm<0, false><<<dim3(4, 8), 256, 0, stream>>>(mu_h, Hn, mu2b, Hn, mu2_b,
                                                   out_mu, Zn, nullptr, 0, Hn);
  k_gemm<0, false><<<dim3(4, 8), 256, 0, stream>>>(lv_h, Hn, lv2b, Hn, lv2_b,
                                                   out_lv, Zn, nullptr, 0, Hn);

  // z = eps * exp(0.5 lv) + mu
  k_z<<<512, 256, 0, stream>>>(out_mu, out_lv, out_z, zb);

  // decoder init: xz = relu(z @ dz_w^T); pose0 -> posering slot 0
  k_gemm<1, false><<<dim3(4, 8), 256, 0, stream>>>(zb, Zn, dzb, Zn, dz_b,
                                                   nullptr, 0, xz, Zn, Zn);
  k_gemm<1, false><<<dim3(4, 8), 256, 0, stream>>>(xz, Zn, p1b, Zn, p1_b,
                                                   nullptr, 0, t1, Zn, Zn);
  k_gemm<0, false><<<dim3(4, 3), 256, 0, stream>>>(t1, Zn, p2b, Zn, p2_b,
                                                   nullptr, 0, posering, Dn, Zn);

  // persistent decoder (120 steps x {LSTM, fused l1l2}, 1 launch)
  {
    void* da[] = {&xz, &posering, &dWih, &dWhh, &dbih, &dbhh, &hringD,
                  &l1b, &l1_b, &l2b, &l2_b, &out_dec, &barD};
    hipLaunchCooperativeKernel((const void*)k_dec_persist, dim3(256), dim3(256),
                               da, (unsigned)DEC_SMEM, stream);
  }
}

// Round 12
// 8025.573 us; speedup vs baseline: 1.7391x; 1.6819x over previous
//
#include <hip/hip_runtime.h>

typedef __bf16 bf16_t;
typedef __bf16 bf16x8 __attribute__((ext_vector_type(8)));
typedef __bf16 bf16x4 __attribute__((ext_vector_type(4)));
typedef float  f32x4  __attribute__((ext_vector_type(4)));

#define DEV __device__ __forceinline__

constexpr int Bn = 256;
constexpr int Ln = 120;
constexpr int Dn = 192;
constexpr int Zn = 512;
constexpr int Hn = 1024;          // H = 2*Z
constexpr int KE = Zn + Hn;       // 1536: encoder lstm K  (x | h)
constexpr int KD = Zn + Dn + Hn;  // 1728: decoder lstm K  (xz | pose | h)
constexpr int CATD = Zn + Dn;     // 704:  decoder non-recurrent input width
constexpr int NBLK = 256;         // persistent grid size

DEV f32x4 mfma16(bf16x8 a, bf16x8 b, f32x4 c) {
  return __builtin_amdgcn_mfma_f32_16x16x32_bf16(a, b, c, 0, 0, 0);
}
DEV bf16x8 ldb8(const bf16_t* p) { return *reinterpret_cast<const bf16x8*>(p); }
DEV float sigf(float x) { return 1.f / (1.f + expf(-x)); }
DEV unsigned short b2u(bf16_t v) { union { bf16_t b; unsigned short u; } x; x.b = v; return x.u; }

// ---- coherent (cross-XCD) loads: sc0 sc1 bypass L1/L2 ----
// issue-only variants: no wait inside; caller must vwait0() before reading outs.
DEV void ld4i(const bf16_t* p0, const bf16_t* p1, const bf16_t* p2, const bf16_t* p3,
              bf16x8& o0, bf16x8& o1, bf16x8& o2, bf16x8& o3) {
  asm volatile(
      "global_load_dwordx4 %0, %4, off sc0 sc1\n\t"
      "global_load_dwordx4 %1, %5, off sc0 sc1\n\t"
      "global_load_dwordx4 %2, %6, off sc0 sc1\n\t"
      "global_load_dwordx4 %3, %7, off sc0 sc1"
      : "=&v"(o0), "=&v"(o1), "=&v"(o2), "=&v"(o3)
      : "v"(p0), "v"(p1), "v"(p2), "v"(p3)
      : "memory");
}
DEV void ld8i(const bf16_t* p0, const bf16_t* p1, const bf16_t* p2, const bf16_t* p3,
              const bf16_t* p4, const bf16_t* p5, const bf16_t* p6, const bf16_t* p7,
              bf16x8& o0, bf16x8& o1, bf16x8& o2, bf16x8& o3,
              bf16x8& o4, bf16x8& o5, bf16x8& o6, bf16x8& o7) {
  asm volatile(
      "global_load_dwordx4 %0, %8, off sc0 sc1\n\t"
      "global_load_dwordx4 %1, %9, off sc0 sc1\n\t"
      "global_load_dwordx4 %2, %10, off sc0 sc1\n\t"
      "global_load_dwordx4 %3, %11, off sc0 sc1\n\t"
      "global_load_dwordx4 %4, %12, off sc0 sc1\n\t"
      "global_load_dwordx4 %5, %13, off sc0 sc1\n\t"
      "global_load_dwordx4 %6, %14, off sc0 sc1\n\t"
      "global_load_dwordx4 %7, %15, off sc0 sc1"
      : "=&v"(o0), "=&v"(o1), "=&v"(o2), "=&v"(o3),
        "=&v"(o4), "=&v"(o5), "=&v"(o6), "=&v"(o7)
      : "v"(p0), "v"(p1), "v"(p2), "v"(p3), "v"(p4), "v"(p5), "v"(p6), "v"(p7)
      : "memory");
}
// wait for ALL outstanding vmem; sched_barrier stops MFMA hoisting above the wait
DEV void vwait0() {
  asm volatile("s_waitcnt vmcnt(0)" ::: "memory");
  __builtin_amdgcn_sched_barrier(0);
}

// ---- coherent stores (write-through to coherence point) ----
DEV void st16c(bf16_t* p, bf16x8 v) {
  asm volatile("global_store_dwordx4 %0, %1, off sc0 sc1" :: "v"(p), "v"(v) : "memory");
}
DEV void st8c(bf16_t* p, bf16x4 v) {
  asm volatile("global_store_dwordx2 %0, %1, off sc0 sc1" :: "v"(p), "v"(v) : "memory");
}
DEV void st2c(bf16_t* p, unsigned short v) {
  asm volatile("global_store_short %0, %1, off sc0 sc1" :: "v"(p), "v"(v) : "memory");
}

// ---- lightweight grid barrier: 8-way distributed arrive, relaxed atomics ----
// layout (unsigned idx): [g*16] g=0..7 group arrive counters (64B apart),
// [128] group-combine counter, [192] release epoch flag. never reset.
DEV void gbar(unsigned* bar, unsigned epoch, int bid) {
  asm volatile("s_waitcnt vmcnt(0)" ::: "memory");  // drain this wave's sc1 stores
  __syncthreads();                                  // all waves drained + arrived
  if (threadIdx.x == 0) {
    int g = bid & 7;                                // 32 blocks per group
    unsigned a = __hip_atomic_fetch_add(bar + g * 16, 1u, __ATOMIC_RELAXED,
                                        __HIP_MEMORY_SCOPE_AGENT);
    if (a == epoch * 32u - 1u) {
      unsigned b = __hip_atomic_fetch_add(bar + 128, 1u, __ATOMIC_RELAXED,
                                          __HIP_MEMORY_SCOPE_AGENT);
      if (b == epoch * 8u - 1u)
        __hip_atomic_store(bar + 192, epoch, __ATOMIC_RELAXED, __HIP_MEMORY_SCOPE_AGENT);
    }
    while (__hip_atomic_load(bar + 192, __ATOMIC_RELAXED, __HIP_MEMORY_SCOPE_AGENT) < epoch)
      __builtin_amdgcn_s_sleep(2);
  }
  __syncthreads();
}

// ---------------- merged weight-cast kernel (f32 -> bf16, 10 tensors) ----------------
__global__ void k_cast_all(
    const float* __restrict__ s0, const float* __restrict__ s1,
    const float* __restrict__ s2, const float* __restrict__ s3,
    const float* __restrict__ s4, const float* __restrict__ s5,
    const float* __restrict__ s6, const float* __restrict__ s7,
    const float* __restrict__ s8, const float* __restrict__ s9,
    bf16_t* __restrict__ d0, bf16_t* __restrict__ d1,
    bf16_t* __restrict__ d2, bf16_t* __restrict__ d3,
    bf16_t* __restrict__ d4, bf16_t* __restrict__ d5,
    bf16_t* __restrict__ d6, bf16_t* __restrict__ d7,
    bf16_t* __restrict__ d8, bf16_t* __restrict__ d9) {
  // group = 4 elements. cumulative group counts:
  // sizes/4: 24576,524288,524288,131072,131072,65536,65536,24576,131072,24576
  const long TOT = 1646592;
  for (long gidx = blockIdx.x * blockDim.x + threadIdx.x; gidx < TOT;
       gidx += (long)gridDim.x * blockDim.x) {
    const float* s; bf16_t* d; long r = gidx;
    if      (r < 24576)                      { s = s0; d = d0; }
    else if ((r -= 24576)   < 524288)        { s = s1; d = d1; }
    else if ((r -= 524288)  < 524288)        { s = s2; d = d2; }
    else if ((r -= 524288)  < 131072)        { s = s3; d = d3; }
    else if ((r -= 131072)  < 131072)        { s = s4; d = d4; }
    else if ((r -= 131072)  < 65536)         { s = s5; d = d5; }
    else if ((r -= 65536)   < 65536)         { s = s6; d = d6; }
    else if ((r -= 65536)   < 24576)         { s = s7; d = d7; }
    else if ((r -= 24576)   < 131072)        { s = s8; d = d8; }
    else    { r -= 131072;                     s = s9; d = d9; }
    float4 v = reinterpret_cast<const float4*>(s)[r];
    bf16x4 o;
    o[0] = (bf16_t)v.x; o[1] = (bf16_t)v.y; o[2] = (bf16_t)v.z; o[3] = (bf16_t)v.w;
    *reinterpret_cast<bf16x4*>(d + 4 * r) = o;
  }
}

// ---------------- layernorm over (L,D) per sample + x passthrough ----------------
__global__ void k_layernorm(const float* __restrict__ x, const float* __restrict__ w,
                            const float* __restrict__ bsh, float* __restrict__ out0,
                            bf16_t* __restrict__ xn) {
  const int n = Ln * Dn;  // 23040
  int b = blockIdx.x;
  const float* xb = x + (long)b * n;
  float s = 0.f, s2 = 0.f;
  for (int i = threadIdx.x; i < n; i += 256) { float v = xb[i]; s += v; s2 += v * v; }
  for (int off = 32; off; off >>= 1) { s += __shfl_down(s, off); s2 += __shfl_down(s2, off); }
  __shared__ float sh[8];
  int wave = threadIdx.x >> 6, lane = threadIdx.x & 63;
  if (lane == 0) { sh[wave] = s; sh[4 + wave] = s2; }
  __syncthreads();
  if (threadIdx.x == 0) {
    float S = sh[0] + sh[1] + sh[2] + sh[3];
    float S2 = sh[4] + sh[5] + sh[6] + sh[7];
    float m = S / n;
    float var = fmaxf(S2 / n - m * m, 0.f);
    sh[0] = m; sh[1] = rsqrtf(var + 1e-5f);
  }
  __syncthreads();
  float m = sh[0], inv = sh[1];
  for (int i = threadIdx.x; i < n; i += 256) {
    float v = xb[i];
    out0[(long)b * n + i] = v;
    xn[(long)b * n + i] = (bf16_t)((v - m) * inv * w[i] + bsh[i]);
  }
}

// ---------------- generic bf16 MFMA GEMM: out = act(A @ W^T + bias) ----------------
template <int ACT, bool XSPERM>
__global__ __launch_bounds__(256) void k_gemm(
    const bf16_t* __restrict__ A, int lda,
    const bf16_t* __restrict__ W, int ldw,
    const float* __restrict__ bias,
    float* __restrict__ outF, long ldoF,
    bf16_t* __restrict__ outB, int ldoB,
    int K) {
  int lane = threadIdx.x & 63, wave = threadIdx.x >> 6;
  int l15 = lane & 15, q = lane >> 4;
  int m0 = blockIdx.x * 64 + (wave >> 1) * 32;
  int n0 = blockIdx.y * 64 + (wave & 1) * 32;
  f32x4 acc00 = {}, acc01 = {}, acc10 = {}, acc11 = {};
  const bf16_t* Ap = A + (long)(m0 + l15) * lda + q * 8;
  const bf16_t* Wp = W + (long)(n0 + l15) * ldw + q * 8;
  long a16 = (long)16 * lda, w16 = (long)16 * ldw;
  for (int k0 = 0; k0 < K; k0 += 32) {
    bf16x8 a0 = ldb8(Ap + k0);
    bf16x8 a1 = ldb8(Ap + a16 + k0);
    bf16x8 b0 = ldb8(Wp + k0);
    bf16x8 b1 = ldb8(Wp + w16 + k0);
    acc00 = mfma16(a0, b0, acc00);
    acc01 = mfma16(a0, b1, acc01);
    acc10 = mfma16(a1, b0, acc10);
    acc11 = mfma16(a1, b1, acc11);
  }
#pragma unroll
  for (int mi = 0; mi < 2; ++mi)
#pragma unroll
    for (int ni = 0; ni < 2; ++ni) {
      f32x4 acc = (mi == 0) ? (ni == 0 ? acc00 : acc01) : (ni == 0 ? acc10 : acc11);
#pragma unroll
      for (int r = 0; r < 4; ++r) {
        int m = m0 + mi * 16 + q * 4 + r;
        int nn = n0 + ni * 16 + l15;
        float v = acc[r] + bias[nn];
        if (ACT == 1) v = fmaxf(v, 0.f);
        if (outF) outF[(long)m * ldoF + nn] = v;
        if (outB) {
          long row = XSPERM ? ((long)(m % Ln) * Bn + m / Ln) : m;
          outB[row * (long)ldoB + nn] = (bf16_t)v;
        }
      }
    }
}

// ================= persistent encoder BiLSTM =================
constexpr int ENC_CH = KE / 32;                          // 48 k-chunks
constexpr int ENC_SMEM_W = 2 * ENC_CH * 64 * 16;         // 98304 B
constexpr int ENC_SMEM_G = 4 * 64 * 33 * 4;              // 33792 B gate buffers
constexpr int ENC_SMEM = ENC_SMEM_W + ENC_SMEM_G + 128;  // 132224 B

__global__ __launch_bounds__(256, 1) void k_enc_persist(
    const bf16_t* __restrict__ xs,   // [L][B][Z]
    const float* __restrict__ WihF, const float* __restrict__ WhhF,
    const float* __restrict__ bihF, const float* __restrict__ bhhF,
    const float* __restrict__ WihB, const float* __restrict__ WhhB,
    const float* __restrict__ bihB, const float* __restrict__ bhhB,
    const int* __restrict__ lens,
    bf16_t* __restrict__ hf0, bf16_t* __restrict__ hf1,
    bf16_t* __restrict__ hb0, bf16_t* __restrict__ hb1,
    bf16_t* __restrict__ pooledb, float* __restrict__ out_len,
    unsigned* bar) {
  extern __shared__ char smem[];
  bf16x8* Wl = (bf16x8*)smem;
  float* Gbuf = (float*)(smem + ENC_SMEM_W);
  float* bias_l = (float*)(smem + ENC_SMEM_W + ENC_SMEM_G);

  int bid = blockIdx.x;
  int dir = bid >> 7;
  int j0 = (bid & 127) * 8;
  const float* Wih = dir ? WihB : WihF;
  const float* Whh = dir ? WhhB : WhhF;
  const float* bih = dir ? bihB : bihF;
  const float* bhh = dir ? bhhB : bhhF;
  bf16_t* h0 = dir ? hb0 : hf0;
  bf16_t* h1 = dir ? hb1 : hf1;

  int tid = threadIdx.x;
  // ---- stage weight slice into LDS (fragment-major), f32 -> bf16 on the fly
  for (int f = tid; f < 2 * ENC_CH * 64; f += 256) {
    int ni = f / (ENC_CH * 64);
    int rem = f - ni * (ENC_CH * 64);
    int c = rem >> 6, sub = rem & 63;
    int sl = sub & 15, sq = sub >> 4;
    int r = ni * 16 + sl;                      // local W row 0..31
    int grow = (r >> 3) * Hn + j0 + (r & 7);   // global row: gate*H + col
    int k = c * 32 + sq * 8;
    const float* src = (k < Zn) ? (Wih + (long)grow * Zn + k)
                                : (Whh + (long)grow * Hn + (k - Zn));
    bf16x8 v;
#pragma unroll
    for (int e = 0; e < 8; ++e) v[e] = (bf16_t)src[e];
    Wl[f] = v;
  }
  if (tid < 32) {
    int grow = (tid >> 3) * Hn + j0 + (tid & 7);
    bias_l[tid] = bih[grow] + bhh[grow];
  }
  if (bid == 0) out_len[tid] = (float)lens[tid];
  __syncthreads();

  int wave = tid >> 6, lane = tid & 63;
  int l15 = lane & 15, q = lane >> 4;
  int mrow = wave * 64 + l15;      // + mi*16 -> A-frag rows
  int m = wave * 64 + lane;        // pointwise: this thread owns batch row m
  int mylen = lens[m];
  float c_reg[8] = {}, h_reg[8] = {}, pool_reg[8] = {};
  float* Gw = Gbuf + wave * (64 * 33);
  const bf16x8* Wl0 = Wl;
  const bf16x8* Wl1 = Wl + ENC_CH * 64;
  const long h16 = (long)16 * Hn;

#define ENC_HISS(A, c) do { long hk_ = (long)(c) * 32 - Zn;                               \
    ld8i(hrow + hk_,            hrow + h16 + hk_,                                         \
         hrow + 2 * h16 + hk_,  hrow + 3 * h16 + hk_,                                     \
         hrow + hk_ + 32,       hrow + h16 + hk_ + 32,                                    \
         hrow + 2 * h16 + hk_ + 32, hrow + 3 * h16 + hk_ + 32,                            \
         A[0], A[1], A[2], A[3], A[4], A[5], A[6], A[7]); } while (0)
#define ENC_HCONS(A, c) do {                                                              \
    { bf16x8 b0 = Wl0[(c) * 64 + lane], b1 = Wl1[(c) * 64 + lane];                        \
      acc[0][0] = mfma16(A[0], b0, acc[0][0]); acc[0][1] = mfma16(A[0], b1, acc[0][1]);   \
      acc[1][0] = mfma16(A[1], b0, acc[1][0]); acc[1][1] = mfma16(A[1], b1, acc[1][1]);   \
      acc[2][0] = mfma16(A[2], b0, acc[2][0]); acc[2][1] = mfma16(A[2], b1, acc[2][1]);   \
      acc[3][0] = mfma16(A[3], b0, acc[3][0]); acc[3][1] = mfma16(A[3], b1, acc[3][1]); } \
    { bf16x8 b0 = Wl0[((c) + 1) * 64 + lane], b1 = Wl1[((c) + 1) * 64 + lane];            \
      acc[0][0] = mfma16(A[4], b0, acc[0][0]); acc[0][1] = mfma16(A[4], b1, acc[0][1]);   \
      acc[1][0] = mfma16(A[5], b0, acc[1][0]); acc[1][1] = mfma16(A[5], b1, acc[1][1]);   \
      acc[2][0] = mfma16(A[6], b0, acc[2][0]); acc[2][1] = mfma16(A[6], b1, acc[2][1]);   \
      acc[3][0] = mfma16(A[7], b0, acc[3][0]); acc[3][1] = mfma16(A[7], b1, acc[3][1]); } \
  } while (0)
#define ENC_STEP(Acur, Anext, c) vwait0(); ENC_HISS(Anext, (c) + 2); ENC_HCONS(Acur, c);

  for (int t = 0; t < Ln; ++t) {
    int tt = dir ? (Ln - 1 - t) : t;
    const bf16_t* xt = xs + (long)tt * Bn * Zn;
    const bf16_t* hprev = (t & 1) ? h1 : h0;
    bf16_t* hcur = (t & 1) ? h0 : h1;

    f32x4 acc[4][2] = {};
    const bf16_t* xrow = xt + (long)mrow * Zn + q * 8;
    const bf16_t* hrow = hprev + (long)mrow * Hn + q * 8;

    bf16x8 HA[8], HB[8];
    ENC_HISS(HA, 16);                 // prefetch first h batch under x loop
    // x part: immutable -> normal cached loads
    for (int c = 0; c < Zn / 32; ++c) {
      bf16x8 b0 = Wl0[c * 64 + lane];
      bf16x8 b1 = Wl1[c * 64 + lane];
#pragma unroll
      for (int mi = 0; mi < 4; ++mi) {
        bf16x8 a = ldb8(xrow + (long)mi * 16 * Zn + c * 32);
        acc[mi][0] = mfma16(a, b0, acc[mi][0]);
        acc[mi][1] = mfma16(a, b1, acc[mi][1]);
      }
    }
    // h part: coherent, 2-deep pipelined batches of 2 chunks x 4 mi
    ENC_STEP(HA, HB, 16) ENC_STEP(HB, HA, 18) ENC_STEP(HA, HB, 20) ENC_STEP(HB, HA, 22)
    ENC_STEP(HA, HB, 24) ENC_STEP(HB, HA, 26) ENC_STEP(HA, HB, 28) ENC_STEP(HB, HA, 30)
    ENC_STEP(HA, HB, 32) ENC_STEP(HB, HA, 34) ENC_STEP(HA, HB, 36) ENC_STEP(HB, HA, 38)
    ENC_STEP(HA, HB, 40) ENC_STEP(HB, HA, 42) ENC_STEP(HA, HB, 44)
    vwait0(); ENC_HCONS(HB, 46);

    // dump gates to wave-private LDS (row = m-local, col = gate*8 + j-local)
#pragma unroll
    for (int mi = 0; mi < 4; ++mi)
#pragma unroll
      for (int ni = 0; ni < 2; ++ni)
#pragma unroll
        for (int r = 0; r < 4; ++r)
          Gw[(mi * 16 + q * 4 + r) * 33 + ni * 16 + l15] = acc[mi][ni][r];
    __syncthreads();
    bool act = tt < mylen;
    const float* Gr = Gw + lane * 33;
    bf16x8 hpack;
#pragma unroll
    for (int jj = 0; jj < 8; ++jj) {
      float Gi = Gr[jj] + bias_l[jj];
      float Gf = Gr[8 + jj] + bias_l[8 + jj];
      float Gg = Gr[16 + jj] + bias_l[16 + jj];
      float Go = Gr[24 + jj] + bias_l[24 + jj];
      float cn = sigf(Gf) * c_reg[jj] + sigf(Gi) * tanhf(Gg);
      float hn = sigf(Go) * tanhf(cn);
      if (act) { c_reg[jj] = cn; h_reg[jj] = hn; pool_reg[jj] += hn; }
      hpack[jj] = (bf16_t)h_reg[jj];
    }
    st16c(hcur + (long)m * Hn + j0, hpack);
    if (t != Ln - 1) gbar(bar, (unsigned)(t + 1), bid);
  }
#undef ENC_STEP
#undef ENC_HCONS
#undef ENC_HISS
  // pooled / len  (bf16 for the mu/lv heads)
  bf16x8 pp;
#pragma unroll
  for (int jj = 0; jj < 8; ++jj) pp[jj] = (bf16_t)(pool_reg[jj] / (float)mylen);
  *(bf16x8*)(pooledb + (long)m * (2 * Hn) + dir * Hn + j0) = pp;
}

// ================= persistent decoder (LSTM + l1 + l2 per step) =================
constexpr int DEC_CH = KD / 32;                          // 54 k-chunks
constexpr int DEC_SMEM_W = 2 * DEC_CH * 64 * 16;         // 110592 B
constexpr int DEC_SMEM_G = 4 * 32 * 33 * 4;              // 16896 B
constexpr int DEC_SMEM = DEC_SMEM_W + DEC_SMEM_G + 128;  // 127616 B

__global__ __launch_bounds__(256, 1) void k_dec_persist(
    bf16_t* __restrict__ inp,        // [B][CATD]  xz | pose (pose updated here)
    const float* __restrict__ dWih, const float* __restrict__ dWhh,
    const float* __restrict__ dbih, const float* __restrict__ dbhh,
    bf16_t* __restrict__ h_in0, bf16_t* __restrict__ h_in1,
    const bf16_t* __restrict__ l1w, const float* __restrict__ l1bias,
    const bf16_t* __restrict__ l2w, const float* __restrict__ l2bias,
    bf16_t* __restrict__ t1,         // [B][Zn] bf16 scratch
    float* __restrict__ out_dec,
    unsigned* bar) {
  extern __shared__ char smem[];
  bf16x8* Wl = (bf16x8*)smem;
  float* Gbuf = (float*)(smem + DEC_SMEM_W);
  float* bias_l = (float*)(smem + DEC_SMEM_W + DEC_SMEM_G);

  int bid = blockIdx.x;
  int mbase = (bid >> 7) * 128;
  int j0 = (bid & 127) * 8;
  int tid = threadIdx.x;

  for (int f = tid; f < 2 * DEC_CH * 64; f += 256) {
    int ni = f / (DEC_CH * 64);
    int rem = f - ni * (DEC_CH * 64);
    int c = rem >> 6, sub = rem & 63;
    int sl = sub & 15, sq = sub >> 4;
    int r = ni * 16 + sl;
    int grow = (r >> 3) * Hn + j0 + (r & 7);
    int k = c * 32 + sq * 8;
    const float* src = (k < CATD) ? (dWih + (long)grow * CATD + k)
                                  : (dWhh + (long)grow * Hn + (k - CATD));
    bf16x8 v;
#pragma unroll
    for (int e = 0; e < 8; ++e) v[e] = (bf16_t)src[e];
    Wl[f] = v;
  }
  if (tid < 32) {
    int grow = (tid >> 3) * Hn + j0 + (tid & 7);
    bias_l[tid] = dbih[grow] + dbhh[grow];
  }
  __syncthreads();

  int wave = tid >> 6, lane = tid & 63;
  int l15 = lane & 15, q = lane >> 4;
  int mrow = mbase + wave * 32 + l15;          // + mi*16
  int mpt = mbase + wave * 32 + (lane >> 1);   // pointwise m
  int jh = (lane & 1) * 4;                     // pointwise j-half
  float c_reg[4] = {};
  float* Gw = Gbuf + wave * (32 * 33);
  int gw = bid * 4 + wave;                     // global wave id (0..1023)
  const bf16x8* Wl0 = Wl;
  const bf16x8* Wl1 = Wl + DEC_CH * 64;
  const long i16 = (long)16 * CATD;
  const long h16d = (long)16 * Hn;

#define DEC_HISS(A, c) do { long hk_ = (long)(c) * 32 - CATD;                             \
    ld8i(hrow + hk_,        hrow + h16d + hk_,                                            \
         hrow + hk_ + 32,   hrow + h16d + hk_ + 32,                                       \
         hrow + hk_ + 64,   hrow + h16d + hk_ + 64,                                       \
         hrow + hk_ + 96,   hrow + h16d + hk_ + 96,                                       \
         A[0], A[1], A[2], A[3], A[4], A[5], A[6], A[7]); } while (0)
#define DEC_HCONS(A, c) do {                                                              \
    { bf16x8 b0 = Wl0[(c) * 64 + lane], b1 = Wl1[(c) * 64 + lane];                        \
      acc[0][0] = mfma16(A[0], b0, acc[0][0]); acc[0][1] = mfma16(A[0], b1, acc[0][1]);   \
      acc[1][0] = mfma16(A[1], b0, acc[1][0]); acc[1][1] = mfma16(A[1], b1, acc[1][1]); } \
    { bf16x8 b0 = Wl0[((c) + 1) * 64 + lane], b1 = Wl1[((c) + 1) * 64 + lane];            \
      acc[0][0] = mfma16(A[2], b0, acc[0][0]); acc[0][1] = mfma16(A[2], b1, acc[0][1]);   \
      acc[1][0] = mfma16(A[3], b0, acc[1][0]); acc[1][1] = mfma16(A[3], b1, acc[1][1]); } \
    { bf16x8 b0 = Wl0[((c) + 2) * 64 + lane], b1 = Wl1[((c) + 2) * 64 + lane];            \
      acc[0][0] = mfma16(A[4], b0, acc[0][0]); acc[0][1] = mfma16(A[4], b1, acc[0][1]);   \
      acc[1][0] = mfma16(A[5], b0, acc[1][0]); acc[1][1] = mfma16(A[5], b1, acc[1][1]); } \
    { bf16x8 b0 = Wl0[((c) + 3) * 64 + lane], b1 = Wl1[((c) + 3) * 64 + lane];            \
      acc[0][0] = mfma16(A[6], b0, acc[0][0]); acc[0][1] = mfma16(A[6], b1, acc[0][1]);   \
      acc[1][0] = mfma16(A[7], b0, acc[1][0]); acc[1][1] = mfma16(A[7], b1, acc[1][1]); } \
  } while (0)

  for (int t = 0; t < Ln; ++t) {
    const bf16_t* hprev = (t & 1) ? h_in1 : h_in0;
    bf16_t* hcur = (t & 1) ? h_in0 : h_in1;

    // ---- phase 1: LSTM gates + pointwise
    f32x4 acc[2][2] = {};
    const bf16_t* irow = inp + (long)mrow * CATD + q * 8;
    const bf16_t* hrow = hprev + (long)mrow * Hn + q * 8;

    // prefetch pose (12 loads) + first h batch (8 loads) under the xz loop
    bf16x8 P0, P1, P2, P3, P4, P5, P6, P7, P8, P9, P10, P11;
    ld8i(irow + 16 * 32, irow + i16 + 16 * 32, irow + 17 * 32, irow + i16 + 17 * 32,
         irow + 18 * 32, irow + i16 + 18 * 32, irow + 19 * 32, irow + i16 + 19 * 32,
         P0, P1, P2, P3, P4, P5, P6, P7);
    ld4i(irow + 20 * 32, irow + i16 + 20 * 32, irow + 21 * 32, irow + i16 + 21 * 32,
         P8, P9, P10, P11);
    bf16x8 HA[8], HB[8];
    DEC_HISS(HA, 22);

    // xz chunks (c=0..15): immutable -> cached
    for (int c = 0; c < Zn / 32; ++c) {
      bf16x8 b0 = Wl0[c * 64 + lane];
      bf16x8 b1 = Wl1[c * 64 + lane];
#pragma unroll
      for (int mi = 0; mi < 2; ++mi) {
        bf16x8 a = ldb8(irow + (long)mi * 16 * CATD + c * 32);
        acc[mi][0] = mfma16(a, b0, acc[mi][0]);
        acc[mi][1] = mfma16(a, b1, acc[mi][1]);
      }
    }
    vwait0();
    DEC_HISS(HB, 26);
    // consume pose (chunks 16..21)
    { bf16x8 b0 = Wl0[16 * 64 + lane], b1 = Wl1[16 * 64 + lane];
      acc[0][0] = mfma16(P0, b0, acc[0][0]); acc[0][1] = mfma16(P0, b1, acc[0][1]);
      acc[1][0] = mfma16(P1, b0, acc[1][0]); acc[1][1] = mfma16(P1, b1, acc[1][1]); }
    { bf16x8 b0 = Wl0[17 * 64 + lane], b1 = Wl1[17 * 64 + lane];
      acc[0][0] = mfma16(P2, b0, acc[0][0]); acc[0][1] = mfma16(P2, b1, acc[0][1]);
      acc[1][0] = mfma16(P3, b0, acc[1][0]); acc[1][1] = mfma16(P3, b1, acc[1][1]); }
    { bf16x8 b0 = Wl0[18 * 64 + lane], b1 = Wl1[18 * 64 + lane];
      acc[0][0] = mfma16(P4, b0, acc[0][0]); acc[0][1] = mfma16(P4, b1, acc[0][1]);
      acc[1][0] = mfma16(P5, b0, acc[1][0]); acc[1][1] = mfma16(P5, b1, acc[1][1]); }
    { bf16x8 b0 = Wl0[19 * 64 + lane], b1 = Wl1[19 * 64 + lane];
      acc[0][0] = mfma16(P6, b0, acc[0][0]); acc[0][1] = mfma16(P6, b1, acc[0][1]);
      acc[1][0] = mfma16(P7, b0, acc[1][0]); acc[1][1] = mfma16(P7, b1, acc[1][1]); }
    { bf16x8 b0 = Wl0[20 * 64 + lane], b1 = Wl1[20 * 64 + lane];
      acc[0][0] = mfma16(P8, b0, acc[0][0]); acc[0][1] = mfma16(P8, b1, acc[0][1]);
      acc[1][0] = mfma16(P9, b0, acc[1][0]); acc[1][1] = mfma16(P9, b1, acc[1][1]); }
    { bf16x8 b0 = Wl0[21 * 64 + lane], b1 = Wl1[21 * 64 + lane];
      acc[0][0] = mfma16(P10, b0, acc[0][0]); acc[0][1] = mfma16(P10, b1, acc[0][1]);
      acc[1][0] = mfma16(P11, b0, acc[1][0]); acc[1][1] = mfma16(P11, b1, acc[1][1]); }
    DEC_HCONS(HA, 22);
    vwait0(); DEC_HISS(HA, 30); DEC_HCONS(HB, 26);
    vwait0(); DEC_HISS(HB, 34); DEC_HCONS(HA, 30);
    vwait0(); DEC_HISS(HA, 38); DEC_HCONS(HB, 34);
    vwait0(); DEC_HISS(HB, 42); DEC_HCONS(HA, 38);
    vwait0(); DEC_HISS(HA, 46); DEC_HCONS(HB, 42);
    vwait0(); DEC_HISS(HB, 50); DEC_HCONS(HA, 46);
    vwait0(); DEC_HCONS(HB, 50);

#pragma unroll
    for (int mi = 0; mi < 2; ++mi)
#pragma unroll
      for (int ni = 0; ni < 2; ++ni)
#pragma unroll
        for (int r = 0; r < 4; ++r)
          Gw[(mi * 16 + q * 4 + r) * 33 + ni * 16 + l15] = acc[mi][ni][r];
    __syncthreads();
    {
      const float* Gr = Gw + (lane >> 1) * 33 + jh;
      bf16x4 hp;
#pragma unroll
      for (int p = 0; p < 4; ++p) {
        float Gi = Gr[p] + bias_l[jh + p];
        float Gf = Gr[8 + p] + bias_l[8 + jh + p];
        float Gg = Gr[16 + p] + bias_l[16 + jh + p];
        float Go = Gr[24 + p] + bias_l[24 + jh + p];
        float cn = sigf(Gf) * c_reg[p] + sigf(Gi) * tanhf(Gg);
        c_reg[p] = cn;
        hp[p] = (bf16_t)(sigf(Go) * tanhf(cn));
      }
      st8c(hcur + (long)mpt * Hn + j0 + jh, hp);
    }
    gbar(bar, (unsigned)(3 * t + 1), bid);

    // ---- phase 2: t1 = relu(h @ l1w^T + l1bias)   (16 x 32 tiles)
    if (gw < 512) {
      int mt = gw >> 5, nt = gw & 31;
      f32x4 a1 = {};
      const bf16_t* ha = hcur + (long)(mt * 16 + l15) * Hn + q * 8;
      const bf16_t* wb = l1w + (long)(nt * 16 + l15) * Hn + q * 8;
      bf16x8 QA[8], QB[8];
#define P2_ISS(A, c0) ld8i(ha + ((c0) + 0) * 32, ha + ((c0) + 1) * 32,                    \
                           ha + ((c0) + 2) * 32, ha + ((c0) + 3) * 32,                    \
                           ha + ((c0) + 4) * 32, ha + ((c0) + 5) * 32,                    \
                           ha + ((c0) + 6) * 32, ha + ((c0) + 7) * 32,                    \
                           A[0], A[1], A[2], A[3], A[4], A[5], A[6], A[7])
      P2_ISS(QA, 0);
      vwait0(); P2_ISS(QB, 8);
#pragma unroll
      for (int k = 0; k < 8; ++k) a1 = mfma16(QA[k], ldb8(wb + k * 32), a1);
      vwait0(); P2_ISS(QA, 16);
#pragma unroll
      for (int k = 0; k < 8; ++k) a1 = mfma16(QB[k], ldb8(wb + (8 + k) * 32), a1);
      vwait0(); P2_ISS(QB, 24);
#pragma unroll
      for (int k = 0; k < 8; ++k) a1 = mfma16(QA[k], ldb8(wb + (16 + k) * 32), a1);
      vwait0();
#pragma unroll
      for (int k = 0; k < 8; ++k) a1 = mfma16(QB[k], ldb8(wb + (24 + k) * 32), a1);
#undef P2_ISS
      int n = nt * 16 + l15;
      float bb = l1bias[n];
#pragma unroll
      for (int r = 0; r < 4; ++r) {
        float v = fmaxf(a1[r] + bb, 0.f);
        st2c(t1 + (long)(mt * 16 + q * 4 + r) * Zn + n, b2u((bf16_t)v));
      }
    }
    gbar(bar, (unsigned)(3 * t + 2), bid);

    // ---- phase 3: pose = t1 @ l2w^T + l2bias -> out_dec & inp[:, Zn:]
    if (gw < 192) {
      int mt = gw / 12, nt = gw - mt * 12;
      f32x4 a2 = {};
      const bf16_t* ta = t1 + (long)(mt * 16 + l15) * Zn + q * 8;
      const bf16_t* wb = l2w + (long)(nt * 16 + l15) * Zn + q * 8;
      bf16x8 QA[8], QB[8];
      ld8i(ta + 0 * 32, ta + 1 * 32, ta + 2 * 32, ta + 3 * 32,
           ta + 4 * 32, ta + 5 * 32, ta + 6 * 32, ta + 7 * 32,
           QA[0], QA[1], QA[2], QA[3], QA[4], QA[5], QA[6], QA[7]);
      vwait0();
      ld8i(ta + 8 * 32, ta + 9 * 32, ta + 10 * 32, ta + 11 * 32,
           ta + 12 * 32, ta + 13 * 32, ta + 14 * 32, ta + 15 * 32,
           QB[0], QB[1], QB[2], QB[3], QB[4], QB[5], QB[6], QB[7]);
#pragma unroll
      for (int k = 0; k < 8; ++k) a2 = mfma16(QA[k], ldb8(wb + k * 32), a2);
      vwait0();
#pragma unroll
      for (int k = 0; k < 8; ++k) a2 = mfma16(QB[k], ldb8(wb + (8 + k) * 32), a2);
      int n = nt * 16 + l15;
      float bb = l2bias[n];
#pragma unroll
      for (int r = 0; r < 4; ++r) {
        int mm = mt * 16 + q * 4 + r;
        float v = a2[r] + bb;
        out_dec[(long)mm * (Ln * Dn) + (long)t * Dn + n] = v;
        st2c(inp + (long)mm * CATD + Zn + n, b2u((bf16_t)v));
      }
    }
    if (t != Ln - 1) gbar(bar, (unsigned)(3 * t + 3), bid);
  }
#undef DEC_HCONS
#undef DEC_HISS
}

// ---------------- z = eps * exp(0.5 lv) + mu ----------------
DEV unsigned rotl32(unsigned v, int s) { return (v << s) | (v >> (32 - s)); }

#define TF_R4(r0, r1, r2, r3)                       \
  x0 += x1; x1 = rotl32(x1, r0); x1 ^= x0;          \
  x0 += x1; x1 = rotl32(x1, r1); x1 ^= x0;          \
  x0 += x1; x1 = rotl32(x1, r2); x1 ^= x0;          \
  x0 += x1; x1 = rotl32(x1, r3); x1 ^= x0;

DEV float erfinv_xla(float x) {
  float w = -log1pf(-x * x);
  float p;
  if (w < 5.f) {
    w -= 2.5f;
    p = 2.81022636e-08f;
    p = fmaf(p, w, 3.43273939e-07f);
    p = fmaf(p, w, -3.5233877e-06f);
    p = fmaf(p, w, -4.39150654e-06f);
    p = fmaf(p, w, 0.00021858087f);
    p = fmaf(p, w, -0.00125372503f);
    p = fmaf(p, w, -0.00417768164f);
    p = fmaf(p, w, 0.246640727f);
    p = fmaf(p, w, 1.50140941f);
  } else {
    w = sqrtf(w) - 3.f;
    p = -0.000200214257f;
    p = fmaf(p, w, 0.000100950558f);
    p = fmaf(p, w, 0.00134934322f);
    p = fmaf(p, w, -0.00367342844f);
    p = fmaf(p, w, 0.00573950773f);
    p = fmaf(p, w, -0.0076224613f);
    p = fmaf(p, w, 0.00943887047f);
    p = fmaf(p, w, 1.00167406f);
    p = fmaf(p, w, 2.83297682f);
  }
  return p * x;
}

__global__ void k_z(const float* __restrict__ mu, const float* __restrict__ lv,
                    float* __restrict__ zf, bf16_t* __restrict__ zb) {
  int i = blockIdx.x * blockDim.x + threadIdx.x;  // 0..131071
  const unsigned ks0 = 0u, ks1 = 42u, ks2 = 0x1BD11BDAu ^ ks0 ^ ks1;
  unsigned x0 = 0u + ks0;
  unsigned x1 = (unsigned)i + ks1;
  TF_R4(13, 15, 26, 6);  x0 += ks1; x1 += ks2 + 1u;
  TF_R4(17, 29, 16, 24); x0 += ks2; x1 += ks0 + 2u;
  TF_R4(13, 15, 26, 6);  x0 += ks0; x1 += ks1 + 3u;
  TF_R4(17, 29, 16, 24); x0 += ks1; x1 += ks2 + 4u;
  TF_R4(13, 15, 26, 6);  x0 += ks2; x1 += ks0 + 5u;
  unsigned bits = x0 ^ x1;
  float f = __uint_as_float((bits >> 9) | 0x3F800000u) - 1.0f;
  float u = f * 2.0f + (-0.99999994f);
  u = fmaxf(u, -0.99999994f);
  float e = 1.41421356f * erfinv_xla(u);
  float zv = e * expf(0.5f * lv[i]) + mu[i];
  zf[i] = zv;
  zb[i] = (bf16_t)zv;
}

// ---------------- host ----------------
extern "C" void kernel_launch(void* const* d_in, const int* in_sizes, int n_in,
                              void* d_out, int out_size, void* d_ws, size_t ws_size,
                              hipStream_t stream) {
  const float* x     = (const float*)d_in[0];
  const int*   lens  = (const int*)d_in[1];
  const float* ln_w  = (const float*)d_in[2];
  const float* ln_b  = (const float*)d_in[3];
  const float* enc_w = (const float*)d_in[4];
  const float* enc_b = (const float*)d_in[5];
  const float* Wih_f = (const float*)d_in[6];
  const float* Whh_f = (const float*)d_in[7];
  const float* bih_f = (const float*)d_in[8];
  const float* bhh_f = (const float*)d_in[9];
  const float* Wih_b = (const float*)d_in[10];
  const float* Whh_b = (const float*)d_in[11];
  const float* bih_b = (const float*)d_in[12];
  const float* bhh_b = (const float*)d_in[13];
  const float* mu1_w = (const float*)d_in[14];
  const float* mu1_b = (const float*)d_in[15];
  const float* mu2_w = (const float*)d_in[16];
  const float* mu2_b = (const float*)d_in[17];
  const float* lv1_w = (const float*)d_in[18];
  const float* lv1_b = (const float*)d_in[19];
  const float* lv2_w = (const float*)d_in[20];
  const float* lv2_b = (const float*)d_in[21];
  const float* dz_w  = (const float*)d_in[22];
  const float* dz_b  = (const float*)d_in[23];
  const float* p1_w  = (const float*)d_in[24];
  const float* p1_b  = (const float*)d_in[25];
  const float* p2_w  = (const float*)d_in[26];
  const float* p2_b  = (const float*)d_in[27];
  const float* dWih  = (const float*)d_in[28];
  const float* dWhh  = (const float*)d_in[29];
  const float* dbih  = (const float*)d_in[30];
  const float* dbhh  = (const float*)d_in[31];
  const float* l1_w  = (const float*)d_in[32];
  const float* l1_b  = (const float*)d_in[33];
  const float* l2_w  = (const float*)d_in[34];
  const float* l2_b  = (const float*)d_in[35];

  float* out0    = (float*)d_out;
  float* out_dec = out0 + (long)Bn * Ln * Dn;
  float* out_len = out_dec + (long)Bn * Ln * Dn;
  float* out_mu  = out_len + Bn;
  float* out_lv  = out_mu + (long)Bn * Zn;
  float* out_z   = out_lv + (long)Bn * Zn;

  char* wp = (char*)d_ws;
  auto alloc = [&](size_t bytes) -> void* {
    void* r = (void*)wp;
    wp += (bytes + 255) & ~(size_t)255;
    return r;
  };

  bf16_t* xn      = (bf16_t*)alloc((size_t)Bn * Ln * Dn * 2);
  bf16_t* xs      = (bf16_t*)alloc((size_t)Ln * Bn * Zn * 2);
  bf16_t* encw    = (bf16_t*)alloc((size_t)Zn * Dn * 2);
  bf16_t* mu1b    = (bf16_t*)alloc((size_t)Hn * 2 * Hn * 2);
  bf16_t* lv1b    = (bf16_t*)alloc((size_t)Hn * 2 * Hn * 2);
  bf16_t* mu2b    = (bf16_t*)alloc((size_t)Zn * Hn * 2);
  bf16_t* lv2b    = (bf16_t*)alloc((size_t)Zn * Hn * 2);
  bf16_t* dzb     = (bf16_t*)alloc((size_t)Zn * Zn * 2);
  bf16_t* p1b     = (bf16_t*)alloc((size_t)Zn * Zn * 2);
  bf16_t* p2b     = (bf16_t*)alloc((size_t)Dn * Zn * 2);
  bf16_t* l1b     = (bf16_t*)alloc((size_t)Zn * Hn * 2);
  bf16_t* l2b     = (bf16_t*)alloc((size_t)Dn * Zn * 2);
  bf16_t* hf0     = (bf16_t*)alloc((size_t)Bn * Hn * 2);
  bf16_t* hf1     = (bf16_t*)alloc((size_t)Bn * Hn * 2);
  bf16_t* hb0     = (bf16_t*)alloc((size_t)Bn * Hn * 2);
  bf16_t* hb1     = (bf16_t*)alloc((size_t)Bn * Hn * 2);
  bf16_t* hd0     = (bf16_t*)alloc((size_t)Bn * Hn * 2);
  bf16_t* hd1     = (bf16_t*)alloc((size_t)Bn * Hn * 2);
  bf16_t* pooledb = (bf16_t*)alloc((size_t)Bn * 2 * Hn * 2);
  bf16_t* mu_h    = (bf16_t*)alloc((size_t)Bn * Hn * 2);
  bf16_t* lv_h    = (bf16_t*)alloc((size_t)Bn * Hn * 2);
  bf16_t* zb      = (bf16_t*)alloc((size_t)Bn * Zn * 2);
  bf16_t* inp     = (bf16_t*)alloc((size_t)Bn * CATD * 2);
  bf16_t* t1      = (bf16_t*)alloc((size_t)Bn * Zn * 2);
  unsigned* bars  = (unsigned*)alloc(2048);   // enc region [0..255], dec region [256..511]
  unsigned* barE  = bars;
  unsigned* barD  = bars + 256;

  static int s_attr_done = 0;
  if (!s_attr_done) {
    (void)hipFuncSetAttribute((const void*)k_enc_persist,
                              hipFuncAttributeMaxDynamicSharedMemorySize, ENC_SMEM);
    (void)hipFuncSetAttribute((const void*)k_dec_persist,
                              hipFuncAttributeMaxDynamicSharedMemorySize, DEC_SMEM);
    s_attr_done = 1;
  }

  // zero-init recurrent state + barrier state
  hipMemsetAsync(hf0, 0, (size_t)Bn * Hn * 2, stream);
  hipMemsetAsync(hb0, 0, (size_t)Bn * Hn * 2, stream);
  hipMemsetAsync(hd0, 0, (size_t)Bn * Hn * 2, stream);
  hipMemsetAsync(bars, 0, 2048, stream);

  // weight prep for the small GEMMs (bf16 casts), single launch
  k_cast_all<<<2048, 256, 0, stream>>>(enc_w, mu1_w, lv1_w, mu2_w, lv2_w,
                                       dz_w, p1_w, p2_w, l1_w, l2_w,
                                       encw, mu1b, lv1b, mu2b, lv2b,
                                       dzb, p1b, p2b, l1b, l2b);

  // layernorm + x passthrough
  k_layernorm<<<256, 256, 0, stream>>>(x, ln_w, ln_b, out0, xn);

  // encoder input: xs[l][b][:] = relu(xn @ enc_w^T + enc_b)
  k_gemm<1, true><<<dim3(480, 8), 256, 0, stream>>>(xn, Dn, encw, Dn, enc_b,
                                                    nullptr, 0, xs, Zn, Dn);

  // persistent BiLSTM encoder (120 steps, 1 launch)
  {
    void* ea[] = {&xs, &Wih_f, &Whh_f, &bih_f, &bhh_f,
                  &Wih_b, &Whh_b, &bih_b, &bhh_b, &lens,
                  &hf0, &hf1, &hb0, &hb1, &pooledb, &out_len, &barE};
    hipLaunchCooperativeKernel((const void*)k_enc_persist, dim3(256), dim3(256),
                               ea, (unsigned)ENC_SMEM, stream);
  }

  // mu / log_var heads
  k_gemm<1, false><<<dim3(4, 16), 256, 0, stream>>>(pooledb, 2 * Hn, mu1b, 2 * Hn, mu1_b,
                                                    nullptr, 0, mu_h, Hn, 2 * Hn);
  k_gemm<1, false><<<dim3(4, 16), 256, 0, stream>>>(pooledb, 2 * Hn, lv1b, 2 * Hn, lv1_b,
                                                    nullptr, 0, lv_h, Hn, 2 * Hn);
  k_gemm<0, false><<<dim3(4, 8), 256, 0, stream>>>(mu_h, Hn, mu2b, Hn, mu2_b,
                                                   out_mu, Zn, nullptr, 0, Hn);
  k_gemm<0, false><<<dim3(4, 8), 256, 0, stream>>>(lv_h, Hn, lv2b, Hn, lv2_b,
                                                   out_lv, Zn, nullptr, 0, Hn);

  // z = eps * exp(0.5 lv) + mu
  k_z<<<512, 256, 0, stream>>>(out_mu, out_lv, out_z, zb);

  // decoder init: xz -> inp[:,0:512]; pose0 -> inp[:,512:704]
  k_gemm<1, false><<<dim3(4, 8), 256, 0, stream>>>(zb, Zn, dzb, Zn, dz_b,
                                                   nullptr, 0, inp, CATD, Zn);
  k_gemm<1, false><<<dim3(4, 8), 256, 0, stream>>>(inp, CATD, p1b, Zn, p1_b,
                                                   nullptr, 0, t1, Zn, Zn);
  k_gemm<0, false><<<dim3(4, 3), 256, 0, stream>>>(t1, Zn, p2b, Zn, p2_b,
                                                   nullptr, 0, inp + Zn, CATD, Zn);

  // persistent decoder (120 steps x {LSTM, l1, l2}, 1 launch)
  {
    void* da[] = {&inp, &dWih, &dWhh, &dbih, &dbhh, &hd0, &hd1,
                  &l1b, &l1_b, &l2b, &l2_b, &t1, &out_dec, &barD};
    hipLaunchCooperativeKernel((const void*)k_dec_persist, dim3(256), dim3(256),
                               da, (unsigned)DEC_SMEM, stream);
  }
}